// Round 9
// baseline (214.763 us; speedup 1.0000x reference)
//
#include <hip/hip_runtime.h>

#define B_ 4
#define S_ 4096
#define E_ 1024
#define H_ 128
#define M_ (B_*S_)   // 16384

typedef __attribute__((ext_vector_type(8))) short bf16x8;
typedef __attribute__((ext_vector_type(4))) float f32x4;
typedef __attribute__((ext_vector_type(2))) unsigned int uint2v;

__device__ inline ushort f2bf(float f) {
  union { float f; unsigned u; } v; v.f = f;
  unsigned r = v.u + 0x7fffu + ((v.u >> 16) & 1u);   // RNE
  return (ushort)(r >> 16);
}
__device__ inline ushort f2h(float f) {              // f32 -> f16 bits (RNE)
  union { _Float16 h; ushort u; } v; v.h = (_Float16)f; return v.u;
}
__device__ inline float h2f(ushort u) {
  union { ushort u; _Float16 h; } v; v.u = u; return (float)v.h;
}

// ---- gfx950 cross-lane primitives (register-file, ~2cyc vs ~120cyc ds_bpermute) ----
__device__ inline void pl16sw(unsigned &x, unsigned &y) {
#if __has_builtin(__builtin_amdgcn_permlane16_swap)
  uint2v r = __builtin_amdgcn_permlane16_swap(x, y, false, false);
  x = r.x; y = r.y;
#else
  asm("v_permlane16_swap_b32 %0, %1" : "+v"(x), "+v"(y));
#endif
}
__device__ inline void pl32sw(unsigned &x, unsigned &y) {
#if __has_builtin(__builtin_amdgcn_permlane32_swap)
  uint2v r = __builtin_amdgcn_permlane32_swap(x, y, false, false);
  x = r.x; y = r.y;
#else
  asm("v_permlane32_swap_b32 %0, %1" : "+v"(x), "+v"(y));
#endif
}
// reduce over the 4 quads (lanes {col, col+16, col+32, col+48}); result broadcast to all
__device__ inline float red4max(float v) {
  union { float f; unsigned u; } a, b;
  a.f = v; b.f = v; pl16sw(a.u, b.u);
  float m1 = fmaxf(a.f, b.f);
  a.f = m1; b.f = m1; pl32sw(a.u, b.u);
  return fmaxf(a.f, b.f);
}
__device__ inline float red4sum(float v) {
  union { float f; unsigned u; } a, b;
  a.f = v; b.f = v; pl16sw(a.u, b.u);
  float s1 = a.f + b.f;
  a.f = s1; b.f = s1; pl32sw(a.u, b.u);
  return a.f + b.f;
}
__device__ inline unsigned cvt_pk_bf16(float lo, float hi) {
  unsigned w;
  asm("v_cvt_pk_bf16_f32 %0, %1, %2" : "=v"(w) : "v"(lo), "v"(hi));
  return w;
}

#define GLLDS16(g, l) __builtin_amdgcn_global_load_lds( \
    (const __attribute__((address_space(1))) void*)(g), \
    (__attribute__((address_space(3))) void*)(l), 16, 0, 0)

// slot base for 64-row tile t at CHUNK=256: nc(t) = (t>>2)+1; base(t) = sum nc(u), u<t
__device__ __host__ inline int tile_base(int t) {
  int a = t >> 2, r = t & 3;
  return 2 * a * (a - 1) + r * a + t;
}
#define NSLOT_ 544   // per batch: tile_base(64)

// ---------- kernel 1: W [1024][128] f32 (x3) -> Wt [3][128][1024] bf16 ----------
__global__ __launch_bounds__(256) void wt_kernel(const float* __restrict__ Wq,
    const float* __restrict__ Wk, const float* __restrict__ Wv,
    ushort* __restrict__ Wt) {
  int bid = blockIdx.x;               // 384 = 3 mats * 4 h-tiles * 32 e-tiles
  int mat = bid >> 7;
  int rem = bid & 127;
  int ht = rem >> 5, et = rem & 31;
  const float* W = mat == 0 ? Wq : (mat == 1 ? Wk : Wv);
  int e0 = et * 32, h0 = ht * 32;
  __shared__ float tl[32][33];
  int t = threadIdx.x;
  int r = t >> 3, c = (t & 7) << 2;
  const float4 f = *(const float4*)(W + (size_t)(e0 + r) * H_ + h0 + c);
  tl[r][c] = f.x; tl[r][c+1] = f.y; tl[r][c+2] = f.z; tl[r][c+3] = f.w;
  __syncthreads();
  ushort4 o;
  o.x = f2bf(tl[c+0][r]); o.y = f2bf(tl[c+1][r]);
  o.z = f2bf(tl[c+2][r]); o.w = f2bf(tl[c+3][r]);
  *(ushort4*)(Wt + ((size_t)mat*H_ + h0 + r) * E_ + e0 + c) = o;
}

// ---------- kernel 2: x f32 -> bf16 (memory-bound) ----------
__global__ __launch_bounds__(256) void xb_kernel(const float* __restrict__ x,
                                                 ushort* __restrict__ xb) {
  size_t i = ((size_t)blockIdx.x * 256 + threadIdx.x) * 8;
  float4 f0 = *(const float4*)(x + i);
  float4 f1 = *(const float4*)(x + i + 4);
  alignas(16) ushort us[8];
  us[0]=f2bf(f0.x); us[1]=f2bf(f0.y); us[2]=f2bf(f0.z); us[3]=f2bf(f0.w);
  us[4]=f2bf(f1.x); us[5]=f2bf(f1.y); us[6]=f2bf(f1.z); us[7]=f2bf(f1.w);
  *(uint4*)(xb + i) = *(uint4*)&us[0];
}

// ---------- kernel 3: QKV GEMM (V epilogue writes tiled [g=key/32][dim][key&31]) ----------
__global__ __launch_bounds__(256, 2) void qkv_gemm(const ushort* __restrict__ xb,
    const ushort* __restrict__ Wt, ushort* __restrict__ qo,
    ushort* __restrict__ ko, ushort* __restrict__ vTo) {
  const int m0 = blockIdx.x * 128;
  const int mat = blockIdx.y;
  const ushort* Bsrc = Wt + (size_t)mat * H_ * E_;
  __shared__ ushort As[2][128 * 64];
  __shared__ ushort Bs[2][128 * 64];
  const int tid = threadIdx.x;
  const int wave = tid >> 6, lane = tid & 63;
  const int col = lane & 15, quad = lane >> 4;
  const int wr = wave >> 1, wc = wave & 1;

  f32x4 acc[4][4];
  #pragma unroll
  for (int i = 0; i < 4; i++)
    #pragma unroll
    for (int j = 0; j < 4; j++) acc[i][j] = (f32x4){0.f,0.f,0.f,0.f};

  const int srow = lane >> 3;
  const int sunit = (lane & 7) ^ srow;
  const int gcol = sunit * 8;

  #define STAGE_QKV(it, bufi) do { \
    _Pragma("unroll") \
    for (int j = 0; j < 4; j++) { \
      int rbase = wave*8 + j*32; \
      GLLDS16(xb + (size_t)(m0 + rbase + srow) * E_ + (it)*64 + gcol, \
              &As[bufi][rbase * 64]); \
      GLLDS16(Bsrc + (size_t)(rbase + srow) * E_ + (it)*64 + gcol, \
              &Bs[bufi][rbase * 64]); \
    } \
  } while (0)

  STAGE_QKV(0, 0);
  __syncthreads();

  for (int it = 0; it < 16; it++) {
    if (it < 15) STAGE_QKV(it + 1, (it + 1) & 1);
    const ushort* a = &As[it & 1][0];
    const ushort* bb = &Bs[it & 1][0];
    #pragma unroll
    for (int kc = 0; kc < 2; kc++) {
      bf16x8 af[4], bf[4];
      #pragma unroll
      for (int mi = 0; mi < 4; mi++) {
        int rr = wr*64 + mi*16 + col;
        af[mi] = *(const bf16x8*)(a + rr*64 + (((kc*4 + quad) ^ (col & 7)) * 8));
      }
      #pragma unroll
      for (int ni = 0; ni < 4; ni++) {
        int rr = wc*64 + ni*16 + col;
        bf[ni] = *(const bf16x8*)(bb + rr*64 + (((kc*4 + quad) ^ (col & 7)) * 8));
      }
      #pragma unroll
      for (int mi = 0; mi < 4; mi++)
        #pragma unroll
        for (int ni = 0; ni < 4; ni++)
          acc[mi][ni] = __builtin_amdgcn_mfma_f32_16x16x32_bf16(af[mi], bf[ni], acc[mi][ni], 0, 0, 0);
    }
    __syncthreads();
  }

  if (mat == 2) {
    int bb = m0 >> 12;
    int sbase = (m0 & 4095) + wr * 64;
    #pragma unroll
    for (int ni = 0; ni < 4; ni++) {
      int n = wc*64 + ni*16 + col;
      #pragma unroll
      for (int mi = 0; mi < 4; mi++) {
        int s = sbase + mi*16 + quad*4;
        ushort4 o;
        o.x = f2bf(acc[mi][ni][0]); o.y = f2bf(acc[mi][ni][1]);
        o.z = f2bf(acc[mi][ni][2]); o.w = f2bf(acc[mi][ni][3]);
        *(ushort4*)(vTo + ((size_t)(bb * 128 + (s >> 5)) * 128 + n) * 32 + (s & 31)) = o;
      }
    }
  } else {
    ushort* dst = (mat == 0 ? qo : ko);
    #pragma unroll
    for (int ni = 0; ni < 4; ni++) {
      int n = wc*64 + ni*16 + col;
      #pragma unroll
      for (int mi = 0; mi < 4; mi++) {
        int row = m0 + wr*64 + mi*16 + quad*4;
        #pragma unroll
        for (int r = 0; r < 4; r++)
          dst[(size_t)(row + r) * H_ + n] = f2bf(acc[mi][ni][r]);
      }
    }
  }
}

// ---------- kernel 4: causal flash, tile-PAIR per WG, CHUNK=256, f16 partials ----------
// R9: TLP is the binding constraint (occupancy ~2.8 waves/CU avg; total wave count is
// fixed by split-K granularity -- the only true parallelism lever). CHUNK 512->256:
// heavy blocks 16->8 iterations (halved serial chain), 576->1088 active blocks
// (~2x resident waves). Opart stored f16 so workspace stays ~50MB. Body = R8's
// proven pair structure (112-reg codegen shape) unchanged.
#define CHUNK_ 256
__global__ __launch_bounds__(256, 2) void flash_kernel(const ushort* __restrict__ q,
    const ushort* __restrict__ k, const ushort* __restrict__ vT,
    ushort* __restrict__ Opart, float* __restrict__ ml) {
  const float SL2E = 0.08838834764831845f * 1.44269504088896340736f;
  int c = blockIdx.x;                         // 0..15
  int tp = 31 - (int)blockIdx.y;              // heavy pairs first
  int b = blockIdx.z;
  if (tp < 2 * c) return;
  int tA = tp * 2, tB = tA + 1;
  int slotA = b * NSLOT_ + tile_base(tA) + c;
  int slotB = b * NSLOT_ + tile_base(tB) + c;

  int wave = threadIdx.x >> 6, lane = threadIdx.x & 63;
  int col = lane & 15, quad = lane >> 4;
  int q0A = tA * 64 + wave * 16;
  int q0B = q0A + 64;
  const ushort* qb = q + (size_t)b * S_ * H_;
  const ushort* kbp = k + (size_t)b * S_ * H_;
  const ushort* vb = vT + (size_t)b * S_ * H_;

  __shared__ ushort kl[3][32 * 128];          // TRIPLE buffer, XOR-swizzled 16B units

  bf16x8 qfA[4], qfB[4];
  {
    const ushort* qpA = qb + (size_t)(q0A + col) * H_ + quad * 8;
    const ushort* qpB = qb + (size_t)(q0B + col) * H_ + quad * 8;
    #pragma unroll
    for (int kc = 0; kc < 4; kc++) {
      qfA[kc] = *(const bf16x8*)(qpA + kc * 32);
      qfB[kc] = *(const bf16x8*)(qpB + kc * 32);
    }
  }

  f32x4 OA[8], OB[8];
  #pragma unroll
  for (int d = 0; d < 8; d++) { OA[d] = (f32x4){0.f,0.f,0.f,0.f}; OB[d] = (f32x4){0.f,0.f,0.f,0.f}; }
  float mA = -1e30f, lA = 0.f, mB = -1e30f, lB = 0.f;

  const int c0 = c * CHUNK_;
  const int kendWG = min(c0 + CHUNK_, tB * 64 + 64);
  const int nblk = (kendWG - c0 + 31) >> 5;   // 4 or 8
  const int qlimA = q0A + 15, qlimB = q0B + 15;

  const int sk0 = wave * 8 + quad;            // staged K rows sk0 and sk0+4
  const int gu0 = (col ^ (sk0 & 15)) * 8;     // pre-swizzled global src unit
  const int gu1 = (col ^ ((sk0 + 4) & 15)) * 8;
  const int lo0 = sk0 * 128 + col * 8;        // LDS offsets within a buffer
  const int lo1 = (sk0 + 4) * 128 + col * 8;

  // TILED V: tile g = c*8 + ib (8KB contiguous), element [h=col+d*16][ks=quad*8..]
  const ushort* vbase = vb + (size_t)c * 8 * 4096 + col * 32 + quad * 8;

  uint4 a0, a1;
  { // prologue: stage block 0 directly to buf 0
    const ushort* kp = kbp + (size_t)(c0 + sk0) * H_;
    a0 = *(const uint4*)(kp + gu0);
    a1 = *(const uint4*)(kp + 4 * H_ + gu1);
    *(uint4*)(&kl[0][lo0]) = a0;
    *(uint4*)(&kl[0][lo1]) = a1;
  }
  if (nblk > 1) { // preload block 1 into regs
    const ushort* kp = kbp + (size_t)(c0 + 32 + sk0) * H_;
    a0 = *(const uint4*)(kp + gu0);
    a1 = *(const uint4*)(kp + 4 * H_ + gu1);
  }
  __syncthreads();

  // QK(0) -> current score state
  f32x4 cB0, cB1, cA0, cA1;
  {
    const ushort* kcur = &kl[0][0];
    bf16x8 kf0[4], kf1[4];
    #pragma unroll
    for (int kc = 0; kc < 4; kc++) {
      int u = quad + kc * 4;
      kf0[kc] = *(const bf16x8*)(kcur + col*128        + ((u ^ col) * 8));
      kf1[kc] = *(const bf16x8*)(kcur + (16 + col)*128 + ((u ^ col) * 8));
    }
    cB0 = (f32x4){0.f,0.f,0.f,0.f}; cB1 = cB0; cA0 = cB0; cA1 = cB0;
    __builtin_amdgcn_s_setprio(1);
    #pragma unroll
    for (int kc = 0; kc < 4; kc++) {
      cB0 = __builtin_amdgcn_mfma_f32_16x16x32_bf16(kf0[kc], qfB[kc], cB0, 0, 0, 0);
      cB1 = __builtin_amdgcn_mfma_f32_16x16x32_bf16(kf1[kc], qfB[kc], cB1, 0, 0, 0);
      cA0 = __builtin_amdgcn_mfma_f32_16x16x32_bf16(kf0[kc], qfA[kc], cA0, 0, 0, 0);
      cA1 = __builtin_amdgcn_mfma_f32_16x16x32_bf16(kf1[kc], qfA[kc], cA1, 0, 0, 0);
    }
    __builtin_amdgcn_s_setprio(0);
  }

  int bw = 1;                                 // LDS buffer that receives K(ib+1)
  for (int ib = 0; ib < nblk; ib++) {
    const int kb0 = c0 + ib * 32;
    const int kb1 = kb0 + 32;
    if (ib + 1 < nblk) {                      // write K(ib+1) regs -> LDS buf bw
      *(uint4*)(&kl[bw][lo0]) = a0;
      *(uint4*)(&kl[bw][lo1]) = a1;
    }
    __syncthreads();
    if (ib + 2 < nblk) {                      // T14: load K(ib+2) regs
      const ushort* kp = kbp + (size_t)(kb0 + 64 + sk0) * H_;
      a0 = *(const uint4*)(kp + gu0);
      a1 = *(const uint4*)(kp + 4 * H_ + gu1);
    }
    // ---- QK(ib+1) -> next state (independent of softmax(ib)/PV(ib) below) ----
    f32x4 nB0 = (f32x4){0.f,0.f,0.f,0.f}, nB1 = nB0, nA0 = nB0, nA1 = nB0;
    if (ib + 1 < nblk && kb1 <= qlimB) {
      const ushort* kcur = &kl[bw][0];
      bf16x8 kf0[4], kf1[4];
      #pragma unroll
      for (int kc = 0; kc < 4; kc++) {
        int u = quad + kc * 4;
        kf0[kc] = *(const bf16x8*)(kcur + col*128        + ((u ^ col) * 8));
        kf1[kc] = *(const bf16x8*)(kcur + (16 + col)*128 + ((u ^ col) * 8));
      }
      __builtin_amdgcn_s_setprio(1);
      #pragma unroll
      for (int kc = 0; kc < 4; kc++) {
        nB0 = __builtin_amdgcn_mfma_f32_16x16x32_bf16(kf0[kc], qfB[kc], nB0, 0, 0, 0);
        nB1 = __builtin_amdgcn_mfma_f32_16x16x32_bf16(kf1[kc], qfB[kc], nB1, 0, 0, 0);
      }
      if (kb1 <= qlimA) {
        #pragma unroll
        for (int kc = 0; kc < 4; kc++) {
          nA0 = __builtin_amdgcn_mfma_f32_16x16x32_bf16(kf0[kc], qfA[kc], nA0, 0, 0, 0);
          nA1 = __builtin_amdgcn_mfma_f32_16x16x32_bf16(kf1[kc], qfA[kc], nA1, 0, 0, 0);
        }
      }
      __builtin_amdgcn_s_setprio(0);
    }
    // ---- iter ib: softmax + PV from current score state ----
    if (kb0 <= qlimB) {                       // wave-uniform
      const bool doA = (kb0 <= qlimA);
      bf16x8 vf03[4];
      #pragma unroll
      for (int j = 0; j < 4; j++)
        vf03[j] = *(const bf16x8*)(vbase + (size_t)ib * 4096 + j * 512);
      // ---- tile B softmax ----
      uint4 pfB4;
      {
        float s[8];
        #pragma unroll
        for (int r = 0; r < 4; r++) { s[r] = cB0[r]; s[4+r] = cB1[r]; }
        if (kb0 + 31 > q0B) {
          #pragma unroll
          for (int r = 0; r < 4; r++) {
            if (kb0 + quad*4 + r      > q0B + col) s[r]   = -1e30f;
            if (kb0 + 16 + quad*4 + r > q0B + col) s[4+r] = -1e30f;
          }
        }
        float cm = s[0];
        #pragma unroll
        for (int j = 1; j < 8; j++) cm = fmaxf(cm, s[j]);
        cm = red4max(cm);
        if (!__all(cm <= mB)) {               // T13 exact skip
          float mn = fmaxf(mB, cm);
          float alpha = exp2f((mB - mn) * SL2E);
          lB *= alpha;
          #pragma unroll
          for (int d = 0; d < 8; d++) OB[d] *= alpha;
          mB = mn;
        }
        float rs = 0.f;
        #pragma unroll
        for (int j = 0; j < 8; j++) { s[j] = exp2f((s[j] - mB) * SL2E); rs += s[j]; }
        lB += red4sum(rs);
        unsigned w0 = cvt_pk_bf16(s[0], s[1]);
        unsigned w1 = cvt_pk_bf16(s[2], s[3]);
        unsigned w2 = cvt_pk_bf16(s[4], s[5]);
        unsigned w3 = cvt_pk_bf16(s[6], s[7]);
        pl32sw(w0, w2); pl32sw(w1, w3);
        pl16sw(w0, w2); pl16sw(w1, w3);
        pfB4 = make_uint4(w0, w1, w2, w3);
      }
      bf16x8 vf47[4];                         // issue while softmaxA runs
      #pragma unroll
      for (int j = 0; j < 4; j++)
        vf47[j] = *(const bf16x8*)(vbase + (size_t)ib * 4096 + (4 + j) * 512);
      // ---- tile A softmax ----
      uint4 pfA4 = make_uint4(0u, 0u, 0u, 0u);
      if (doA) {
        float s[8];
        #pragma unroll
        for (int r = 0; r < 4; r++) { s[r] = cA0[r]; s[4+r] = cA1[r]; }
        if (kb0 + 31 > q0A) {
          #pragma unroll
          for (int r = 0; r < 4; r++) {
            if (kb0 + quad*4 + r      > q0A + col) s[r]   = -1e30f;
            if (kb0 + 16 + quad*4 + r > q0A + col) s[4+r] = -1e30f;
          }
        }
        float cm = s[0];
        #pragma unroll
        for (int j = 1; j < 8; j++) cm = fmaxf(cm, s[j]);
        cm = red4max(cm);
        if (!__all(cm <= mA)) {
          float mn = fmaxf(mA, cm);
          float alpha = exp2f((mA - mn) * SL2E);
          lA *= alpha;
          #pragma unroll
          for (int d = 0; d < 8; d++) OA[d] *= alpha;
          mA = mn;
        }
        float rs = 0.f;
        #pragma unroll
        for (int j = 0; j < 8; j++) { s[j] = exp2f((s[j] - mA) * SL2E); rs += s[j]; }
        lA += red4sum(rs);
        unsigned w0 = cvt_pk_bf16(s[0], s[1]);
        unsigned w1 = cvt_pk_bf16(s[2], s[3]);
        unsigned w2 = cvt_pk_bf16(s[4], s[5]);
        unsigned w3 = cvt_pk_bf16(s[6], s[7]);
        pl32sw(w0, w2); pl32sw(w1, w3);
        pl16sw(w0, w2); pl16sw(w1, w3);
        pfA4 = make_uint4(w0, w1, w2, w3);
      }
      // ---- PV for both tiles (shared vf) ----
      {
        union { uint4 u4; bf16x8 v; } puB, puA;
        puB.u4 = pfB4; puA.u4 = pfA4;
        __builtin_amdgcn_s_setprio(1);
        #pragma unroll
        for (int j = 0; j < 4; j++)
          OB[j] = __builtin_amdgcn_mfma_f32_16x16x32_bf16(vf03[j], puB.v, OB[j], 0, 0, 0);
        if (doA) {
          #pragma unroll
          for (int j = 0; j < 4; j++)
            OA[j] = __builtin_amdgcn_mfma_f32_16x16x32_bf16(vf03[j], puA.v, OA[j], 0, 0, 0);
        }
        #pragma unroll
        for (int j = 0; j < 4; j++)
          OB[4 + j] = __builtin_amdgcn_mfma_f32_16x16x32_bf16(vf47[j], puB.v, OB[4 + j], 0, 0, 0);
        if (doA) {
          #pragma unroll
          for (int j = 0; j < 4; j++)
            OA[4 + j] = __builtin_amdgcn_mfma_f32_16x16x32_bf16(vf47[j], puA.v, OA[4 + j], 0, 0, 0);
        }
        __builtin_amdgcn_s_setprio(0);
      }
    }
    // rotate pipeline state (static names, no dynamic indexing)
    cB0 = nB0; cB1 = nB1; cA0 = nA0; cA1 = nA1;
    bw++; if (bw == 3) bw = 0;
  }

  // f16 partial epilogue: Opart[slot][row 0..63][dim 0..127] half
  ushort* OpA = Opart + (size_t)slotA * (64 * 128) + (size_t)(wave*16 + col) * 128 + quad * 4;
  ushort* OpB = Opart + (size_t)slotB * (64 * 128) + (size_t)(wave*16 + col) * 128 + quad * 4;
  #pragma unroll
  for (int d = 0; d < 8; d++) {
    ushort4 ha, hb;
    ha.x = f2h(OA[d][0]); ha.y = f2h(OA[d][1]); ha.z = f2h(OA[d][2]); ha.w = f2h(OA[d][3]);
    hb.x = f2h(OB[d][0]); hb.y = f2h(OB[d][1]); hb.z = f2h(OB[d][2]); hb.w = f2h(OB[d][3]);
    *(ushort4*)(OpA + d * 16) = ha;
    *(ushort4*)(OpB + d * 16) = hb;
  }
  if (quad == 0) {
    *(float2*)(ml + (size_t)slotA * 128 + (size_t)(wave*16 + col) * 2) = make_float2(mA, lA);
    *(float2*)(ml + (size_t)slotB * 128 + (size_t)(wave*16 + col) * 2) = make_float2(mB, lB);
  }
}

// ---------- kernel 5: combine split-K partials (up to 16 chunks, two-pass, no arrays) ----------
__global__ __launch_bounds__(256) void combine_kernel(const ushort* __restrict__ Opart,
    const float* __restrict__ ml, float* __restrict__ out) {
  const float SL2E = 0.08838834764831845f * 1.44269504088896340736f;
  int tile = blockIdx.x, b = blockIdx.y;
  int nc = (tile >> 2) + 1;
  int base = b * NSLOT_ + tile_base(tile);
  int tid = threadIdx.x;
  int row = tid >> 2;
  int cs = (tid & 3) * 4;
  // pass 1: global max (no local arrays -> no scratch; rule #20)
  float mstar = -1e30f;
  for (int ci = 0; ci < nc; ci++)
    mstar = fmaxf(mstar, ml[(size_t)(base + ci) * 128 + row * 2]);
  // pass 2: weighted accumulate
  float denom = 0.f;
  f32x4 acc[8];
  #pragma unroll
  for (int i = 0; i < 8; i++) acc[i] = (f32x4){0.f,0.f,0.f,0.f};
  for (int ci = 0; ci < nc; ci++) {
    float mc = ml[(size_t)(base + ci) * 128 + row * 2];
    float lc = ml[(size_t)(base + ci) * 128 + row * 2 + 1];
    float w = exp2f((mc - mstar) * SL2E);
    denom += w * lc;
    const ushort* Op = Opart + (size_t)(base + ci) * (64 * 128) + row * 128;
    #pragma unroll
    for (int i = 0; i < 8; i++) {
      ushort4 h = *(const ushort4*)(Op + cs + i * 16);
      acc[i][0] += w * h2f(h.x);
      acc[i][1] += w * h2f(h.y);
      acc[i][2] += w * h2f(h.z);
      acc[i][3] += w * h2f(h.w);
    }
  }
  float inv = 1.f / denom;
  float* o = out + ((size_t)(b * S_) + tile * 64 + row) * H_;
  #pragma unroll
  for (int i = 0; i < 8; i++) {
    f32x4 v = acc[i] * inv;
    *(f32x4*)(o + cs + i * 16) = v;
  }
}

extern "C" void kernel_launch(void* const* d_in, const int* in_sizes, int n_in,
                              void* d_out, int out_size, void* d_ws, size_t ws_size,
                              hipStream_t stream) {
  (void)in_sizes; (void)n_in; (void)out_size; (void)ws_size;
  const float* x  = (const float*)d_in[0];
  const float* Wq = (const float*)d_in[1];
  const float* Wk = (const float*)d_in[2];
  const float* Wv = (const float*)d_in[3];
  float* out = (float*)d_out;
  char* ws = (char*)d_ws;
  ushort* Wt = (ushort*)ws;                                        // 768 KB
  ushort* qb = (ushort*)(ws + 786432);                             // 4 MB each
  ushort* kb = qb + (size_t)M_ * H_;
  ushort* vT = kb + (size_t)M_ * H_;
  ushort* Opart = (ushort*)(ws + 786432 + 3 * (size_t)M_ * H_ * 2); // f16, 34.8 MB
  float* ml = (float*)((char*)Opart + (size_t)4 * NSLOT_ * 64 * 128 * 2);  // 1.1 MB
  ushort* xbuf = (ushort*)Opart;   // alias: xb dead before flash writes Opart

  hipLaunchKernelGGL(wt_kernel,   dim3(384), dim3(256), 0, stream, Wq, Wk, Wv, Wt);
  hipLaunchKernelGGL(xb_kernel,   dim3(8192), dim3(256), 0, stream, x, xbuf);
  hipLaunchKernelGGL(qkv_gemm,    dim3(128, 3), dim3(256), 0, stream, xbuf, Wt, qb, kb, vT);
  hipLaunchKernelGGL(flash_kernel,dim3(16, 32, 4), dim3(256), 0, stream, qb, kb, vT, Opart, ml);
  hipLaunchKernelGGL(combine_kernel, dim3(64, 4), dim3(256), 0, stream, Opart, ml, out);
}

// Round 10
// 209.826 us; speedup vs baseline: 1.0235x; 1.0235x over previous
//
#include <hip/hip_runtime.h>

#define B_ 4
#define S_ 4096
#define E_ 1024
#define H_ 128
#define M_ (B_*S_)   // 16384

typedef __attribute__((ext_vector_type(8))) short bf16x8;
typedef __attribute__((ext_vector_type(4))) float f32x4;
typedef __attribute__((ext_vector_type(2))) unsigned int uint2v;

__device__ inline ushort f2bf(float f) {
  union { float f; unsigned u; } v; v.f = f;
  unsigned r = v.u + 0x7fffu + ((v.u >> 16) & 1u);   // RNE
  return (ushort)(r >> 16);
}

// ---- gfx950 cross-lane primitives (register-file, ~2cyc vs ~120cyc ds_bpermute) ----
__device__ inline void pl16sw(unsigned &x, unsigned &y) {
#if __has_builtin(__builtin_amdgcn_permlane16_swap)
  uint2v r = __builtin_amdgcn_permlane16_swap(x, y, false, false);
  x = r.x; y = r.y;
#else
  asm("v_permlane16_swap_b32 %0, %1" : "+v"(x), "+v"(y));
#endif
}
__device__ inline void pl32sw(unsigned &x, unsigned &y) {
#if __has_builtin(__builtin_amdgcn_permlane32_swap)
  uint2v r = __builtin_amdgcn_permlane32_swap(x, y, false, false);
  x = r.x; y = r.y;
#else
  asm("v_permlane32_swap_b32 %0, %1" : "+v"(x), "+v"(y));
#endif
}
// reduce over the 4 quads (lanes {col, col+16, col+32, col+48}); result broadcast to all
__device__ inline float red4max(float v) {
  union { float f; unsigned u; } a, b;
  a.f = v; b.f = v; pl16sw(a.u, b.u);
  float m1 = fmaxf(a.f, b.f);
  a.f = m1; b.f = m1; pl32sw(a.u, b.u);
  return fmaxf(a.f, b.f);
}
__device__ inline float red4sum(float v) {
  union { float f; unsigned u; } a, b;
  a.f = v; b.f = v; pl16sw(a.u, b.u);
  float s1 = a.f + b.f;
  a.f = s1; b.f = s1; pl32sw(a.u, b.u);
  return a.f + b.f;
}
__device__ inline unsigned cvt_pk_bf16(float lo, float hi) {
  unsigned w;
  asm("v_cvt_pk_bf16_f32 %0, %1, %2" : "=v"(w) : "v"(lo), "v"(hi));
  return w;
}

#define GLLDS16(g, l) __builtin_amdgcn_global_load_lds( \
    (const __attribute__((address_space(1))) void*)(g), \
    (__attribute__((address_space(3))) void*)(l), 16, 0, 0)

// ---------- kernel 1: W [1024][128] f32 (x3) -> Wt [3][128][1024] bf16 ----------
__global__ __launch_bounds__(256) void wt_kernel(const float* __restrict__ Wq,
    const float* __restrict__ Wk, const float* __restrict__ Wv,
    ushort* __restrict__ Wt) {
  int bid = blockIdx.x;               // 384 = 3 mats * 4 h-tiles * 32 e-tiles
  int mat = bid >> 7;
  int rem = bid & 127;
  int ht = rem >> 5, et = rem & 31;
  const float* W = mat == 0 ? Wq : (mat == 1 ? Wk : Wv);
  int e0 = et * 32, h0 = ht * 32;
  __shared__ float tl[32][33];
  int t = threadIdx.x;
  int r = t >> 3, c = (t & 7) << 2;
  const float4 f = *(const float4*)(W + (size_t)(e0 + r) * H_ + h0 + c);
  tl[r][c] = f.x; tl[r][c+1] = f.y; tl[r][c+2] = f.z; tl[r][c+3] = f.w;
  __syncthreads();
  ushort4 o;
  o.x = f2bf(tl[c+0][r]); o.y = f2bf(tl[c+1][r]);
  o.z = f2bf(tl[c+2][r]); o.w = f2bf(tl[c+3][r]);
  *(ushort4*)(Wt + ((size_t)mat*H_ + h0 + r) * E_ + e0 + c) = o;
}

// ---------- kernel 2: x f32 -> bf16 (memory-bound) ----------
__global__ __launch_bounds__(256) void xb_kernel(const float* __restrict__ x,
                                                 ushort* __restrict__ xb) {
  size_t i = ((size_t)blockIdx.x * 256 + threadIdx.x) * 8;
  float4 f0 = *(const float4*)(x + i);
  float4 f1 = *(const float4*)(x + i + 4);
  alignas(16) ushort us[8];
  us[0]=f2bf(f0.x); us[1]=f2bf(f0.y); us[2]=f2bf(f0.z); us[3]=f2bf(f0.w);
  us[4]=f2bf(f1.x); us[5]=f2bf(f1.y); us[6]=f2bf(f1.z); us[7]=f2bf(f1.w);
  *(uint4*)(xb + i) = *(uint4*)&us[0];
}

// ---------- kernel 3: QKV GEMM (V epilogue writes tiled [g=key/32][dim][key&31]) ----------
__global__ __launch_bounds__(256, 2) void qkv_gemm(const ushort* __restrict__ xb,
    const ushort* __restrict__ Wt, ushort* __restrict__ qo,
    ushort* __restrict__ ko, ushort* __restrict__ vTo) {
  const int m0 = blockIdx.x * 128;
  const int mat = blockIdx.y;
  const ushort* Bsrc = Wt + (size_t)mat * H_ * E_;
  __shared__ ushort As[2][128 * 64];
  __shared__ ushort Bs[2][128 * 64];
  const int tid = threadIdx.x;
  const int wave = tid >> 6, lane = tid & 63;
  const int col = lane & 15, quad = lane >> 4;
  const int wr = wave >> 1, wc = wave & 1;

  f32x4 acc[4][4];
  #pragma unroll
  for (int i = 0; i < 4; i++)
    #pragma unroll
    for (int j = 0; j < 4; j++) acc[i][j] = (f32x4){0.f,0.f,0.f,0.f};

  const int srow = lane >> 3;
  const int sunit = (lane & 7) ^ srow;
  const int gcol = sunit * 8;

  #define STAGE_QKV(it, bufi) do { \
    _Pragma("unroll") \
    for (int j = 0; j < 4; j++) { \
      int rbase = wave*8 + j*32; \
      GLLDS16(xb + (size_t)(m0 + rbase + srow) * E_ + (it)*64 + gcol, \
              &As[bufi][rbase * 64]); \
      GLLDS16(Bsrc + (size_t)(rbase + srow) * E_ + (it)*64 + gcol, \
              &Bs[bufi][rbase * 64]); \
    } \
  } while (0)

  STAGE_QKV(0, 0);
  __syncthreads();

  for (int it = 0; it < 16; it++) {
    if (it < 15) STAGE_QKV(it + 1, (it + 1) & 1);
    const ushort* a = &As[it & 1][0];
    const ushort* bb = &Bs[it & 1][0];
    #pragma unroll
    for (int kc = 0; kc < 2; kc++) {
      bf16x8 af[4], bf[4];
      #pragma unroll
      for (int mi = 0; mi < 4; mi++) {
        int rr = wr*64 + mi*16 + col;
        af[mi] = *(const bf16x8*)(a + rr*64 + (((kc*4 + quad) ^ (col & 7)) * 8));
      }
      #pragma unroll
      for (int ni = 0; ni < 4; ni++) {
        int rr = wc*64 + ni*16 + col;
        bf[ni] = *(const bf16x8*)(bb + rr*64 + (((kc*4 + quad) ^ (col & 7)) * 8));
      }
      #pragma unroll
      for (int mi = 0; mi < 4; mi++)
        #pragma unroll
        for (int ni = 0; ni < 4; ni++)
          acc[mi][ni] = __builtin_amdgcn_mfma_f32_16x16x32_bf16(af[mi], bf[ni], acc[mi][ni], 0, 0, 0);
    }
    __syncthreads();
  }

  if (mat == 2) {
    int bb = m0 >> 12;
    int sbase = (m0 & 4095) + wr * 64;
    #pragma unroll
    for (int ni = 0; ni < 4; ni++) {
      int n = wc*64 + ni*16 + col;
      #pragma unroll
      for (int mi = 0; mi < 4; mi++) {
        int s = sbase + mi*16 + quad*4;
        ushort4 o;
        o.x = f2bf(acc[mi][ni][0]); o.y = f2bf(acc[mi][ni][1]);
        o.z = f2bf(acc[mi][ni][2]); o.w = f2bf(acc[mi][ni][3]);
        *(ushort4*)(vTo + ((size_t)(bb * 128 + (s >> 5)) * 128 + n) * 32 + (s & 31)) = o;
      }
    }
  } else {
    ushort* dst = (mat == 0 ? qo : ko);
    #pragma unroll
    for (int ni = 0; ni < 4; ni++) {
      int n = wc*64 + ni*16 + col;
      #pragma unroll
      for (int mi = 0; mi < 4; mi++) {
        int row = m0 + wr*64 + mi*16 + quad*4;
        #pragma unroll
        for (int r = 0; r < 4; r++)
          dst[(size_t)(row + r) * H_ + n] = f2bf(acc[mi][ni][r]);
      }
    }
  }
}

// ---------- kernel 4: causal flash, tile-PAIR per WG, CHUNK=512, gllds K+V ----------
// R10: residency model -- total regs (VGPR+acc) ~190-240 caps residency at 2 blocks/CU;
// target <=170 for 3 blocks/CU. Changes vs R8: (a) drop 2-deep QK pipeline (R7 null,
// frees n-state accs); (b) K AND V staged via global_load_lds (dest lane-linear:
// lane=quad*16+col -> byteoff quad*256+col*16 = lane*16; K swizzle stays on global
// source; V tiled layout is contiguous) -- frees a0/a1, early-issued vf longevity,
// addressing. LDS 32KB (K 2x8KB + V 2x8KB). Compute core = proven R2/R8 pair body.
#define CHUNK_ 512
__global__ __launch_bounds__(256, 2) void flash_kernel(const ushort* __restrict__ q,
    const ushort* __restrict__ k, const ushort* __restrict__ vT,
    float* __restrict__ Opart, float* __restrict__ ml) {
  const float SL2E = 0.08838834764831845f * 1.44269504088896340736f;
  int c = blockIdx.x;
  int tp = 31 - (int)blockIdx.y;              // heavy pairs first
  int b = blockIdx.z;
  if (tp < 4 * c) return;
  int tA = tp * 2, tB = tA + 1;
  int aA = tA >> 3, rA = tA & 7;
  int aB = tB >> 3, rB = tB & 7;
  int slotA = b * 288 + (aA + 1) * (4 * aA + rA) + c;
  int slotB = b * 288 + (aB + 1) * (4 * aB + rB) + c;

  int wave = threadIdx.x >> 6, lane = threadIdx.x & 63;
  int col = lane & 15, quad = lane >> 4;
  int q0A = tA * 64 + wave * 16;
  int q0B = q0A + 64;
  const ushort* qb = q + (size_t)b * S_ * H_;
  const ushort* kbp = k + (size_t)b * S_ * H_;
  const ushort* vb = vT + (size_t)b * S_ * H_;

  __shared__ ushort kl[2][32 * 128];          // K double-buffer (16 KB), src-side swizzle
  __shared__ ushort vl[2][32 * 128];          // V double-buffer (16 KB), tiled-contiguous

  bf16x8 qfA[4], qfB[4];
  {
    const ushort* qpA = qb + (size_t)(q0A + col) * H_ + quad * 8;
    const ushort* qpB = qb + (size_t)(q0B + col) * H_ + quad * 8;
    #pragma unroll
    for (int kc = 0; kc < 4; kc++) {
      qfA[kc] = *(const bf16x8*)(qpA + kc * 32);
      qfB[kc] = *(const bf16x8*)(qpB + kc * 32);
    }
  }

  f32x4 OA[8], OB[8];
  #pragma unroll
  for (int d = 0; d < 8; d++) { OA[d] = (f32x4){0.f,0.f,0.f,0.f}; OB[d] = (f32x4){0.f,0.f,0.f,0.f}; }
  float mA = -1e30f, lA = 0.f, mB = -1e30f, lB = 0.f;

  const int c0 = c * CHUNK_;
  const int kendWG = min(c0 + CHUNK_, tB * 64 + 64);
  const int nblk = (kendWG - c0 + 31) >> 5;
  const int qlimA = q0A + 15, qlimB = q0B + 15;

  const int sk0 = wave * 8 + quad;            // staged K rows sk0 and sk0+4
  const int gu0 = (col ^ (sk0 & 15)) * 8;     // pre-swizzled global src unit
  const int gu1 = (col ^ ((sk0 + 4) & 15)) * 8;
  // V source: tiled [g][dim][ks]; linear copy, lane covers 16B at wave*1024+call*512+lane*8
  const ushort* vsrc = vb + (size_t)c * 16 * 4096 + (size_t)wave * 1024 + lane * 8;

  // K staging LDS dest: wave-uniform base + lane*16B == rows wave*8+quad, unit col  ✓
  #define STAGE_KV(kb, g, bufi) do { \
    GLLDS16(kbp + (size_t)((kb) + sk0) * H_ + gu0,     &kl[bufi][wave * 1024]); \
    GLLDS16(kbp + (size_t)((kb) + sk0 + 4) * H_ + gu1, &kl[bufi][wave * 1024 + 512]); \
    GLLDS16(vsrc + (size_t)(g) * 4096,                 &vl[bufi][wave * 1024]); \
    GLLDS16(vsrc + (size_t)(g) * 4096 + 512,           &vl[bufi][wave * 1024 + 512]); \
  } while (0)

  STAGE_KV(c0, 0, 0);
  __syncthreads();

  for (int ib = 0; ib < nblk; ib++) {
    const int kb0 = c0 + ib * 32;
    if (ib + 1 < nblk) STAGE_KV(kb0 + 32, ib + 1, (ib + 1) & 1);  // T14: drained at barrier
    if (kb0 <= qlimB) {                       // wave-uniform
      const bool doA = (kb0 <= qlimA);
      const ushort* kcur = &kl[ib & 1][0];
      const ushort* vcur = &vl[ib & 1][0];
      // K fragments from LDS
      bf16x8 kf0[4], kf1[4];
      #pragma unroll
      for (int kc = 0; kc < 4; kc++) {
        int u = quad + kc * 4;
        kf0[kc] = *(const bf16x8*)(kcur + col*128        + ((u ^ col) * 8));
        kf1[kc] = *(const bf16x8*)(kcur + (16 + col)*128 + ((u ^ col) * 8));
      }
      // QK^T
      f32x4 sB0 = (f32x4){0.f,0.f,0.f,0.f}, sB1 = sB0, sA0 = sB0, sA1 = sB0;
      __builtin_amdgcn_s_setprio(1);
      #pragma unroll
      for (int kc = 0; kc < 4; kc++) {
        sB0 = __builtin_amdgcn_mfma_f32_16x16x32_bf16(kf0[kc], qfB[kc], sB0, 0, 0, 0);
        sB1 = __builtin_amdgcn_mfma_f32_16x16x32_bf16(kf1[kc], qfB[kc], sB1, 0, 0, 0);
      }
      if (doA) {
        #pragma unroll
        for (int kc = 0; kc < 4; kc++) {
          sA0 = __builtin_amdgcn_mfma_f32_16x16x32_bf16(kf0[kc], qfA[kc], sA0, 0, 0, 0);
          sA1 = __builtin_amdgcn_mfma_f32_16x16x32_bf16(kf1[kc], qfA[kc], sA1, 0, 0, 0);
        }
      }
      __builtin_amdgcn_s_setprio(0);
      // V fragments 0..3 from LDS (issue early; overlap softmax B)
      bf16x8 vf03[4];
      #pragma unroll
      for (int j = 0; j < 4; j++)
        vf03[j] = *(const bf16x8*)(vcur + col * 32 + quad * 8 + j * 512);
      // ---- tile B softmax ----
      uint4 pfB4;
      {
        float s[8];
        #pragma unroll
        for (int r = 0; r < 4; r++) { s[r] = sB0[r]; s[4+r] = sB1[r]; }
        if (kb0 + 31 > q0B) {
          #pragma unroll
          for (int r = 0; r < 4; r++) {
            if (kb0 + quad*4 + r      > q0B + col) s[r]   = -1e30f;
            if (kb0 + 16 + quad*4 + r > q0B + col) s[4+r] = -1e30f;
          }
        }
        float cm = s[0];
        #pragma unroll
        for (int j = 1; j < 8; j++) cm = fmaxf(cm, s[j]);
        cm = red4max(cm);
        if (!__all(cm <= mB)) {               // T13 exact skip
          float mn = fmaxf(mB, cm);
          float alpha = exp2f((mB - mn) * SL2E);
          lB *= alpha;
          #pragma unroll
          for (int d = 0; d < 8; d++) OB[d] *= alpha;
          mB = mn;
        }
        float rs = 0.f;
        #pragma unroll
        for (int j = 0; j < 8; j++) { s[j] = exp2f((s[j] - mB) * SL2E); rs += s[j]; }
        lB += red4sum(rs);
        unsigned w0 = cvt_pk_bf16(s[0], s[1]);
        unsigned w1 = cvt_pk_bf16(s[2], s[3]);
        unsigned w2 = cvt_pk_bf16(s[4], s[5]);
        unsigned w3 = cvt_pk_bf16(s[6], s[7]);
        pl32sw(w0, w2); pl32sw(w1, w3);
        pl16sw(w0, w2); pl16sw(w1, w3);
        pfB4 = make_uint4(w0, w1, w2, w3);
      }
      // V fragments 4..7 (overlap softmax A)
      bf16x8 vf47[4];
      #pragma unroll
      for (int j = 0; j < 4; j++)
        vf47[j] = *(const bf16x8*)(vcur + col * 32 + quad * 8 + (4 + j) * 512);
      // ---- tile A softmax ----
      uint4 pfA4 = make_uint4(0u, 0u, 0u, 0u);
      if (doA) {
        float s[8];
        #pragma unroll
        for (int r = 0; r < 4; r++) { s[r] = sA0[r]; s[4+r] = sA1[r]; }
        if (kb0 + 31 > q0A) {
          #pragma unroll
          for (int r = 0; r < 4; r++) {
            if (kb0 + quad*4 + r      > q0A + col) s[r]   = -1e30f;
            if (kb0 + 16 + quad*4 + r > q0A + col) s[4+r] = -1e30f;
          }
        }
        float cm = s[0];
        #pragma unroll
        for (int j = 1; j < 8; j++) cm = fmaxf(cm, s[j]);
        cm = red4max(cm);
        if (!__all(cm <= mA)) {
          float mn = fmaxf(mA, cm);
          float alpha = exp2f((mA - mn) * SL2E);
          lA *= alpha;
          #pragma unroll
          for (int d = 0; d < 8; d++) OA[d] *= alpha;
          mA = mn;
        }
        float rs = 0.f;
        #pragma unroll
        for (int j = 0; j < 8; j++) { s[j] = exp2f((s[j] - mA) * SL2E); rs += s[j]; }
        lA += red4sum(rs);
        unsigned w0 = cvt_pk_bf16(s[0], s[1]);
        unsigned w1 = cvt_pk_bf16(s[2], s[3]);
        unsigned w2 = cvt_pk_bf16(s[4], s[5]);
        unsigned w3 = cvt_pk_bf16(s[6], s[7]);
        pl32sw(w0, w2); pl32sw(w1, w3);
        pl16sw(w0, w2); pl16sw(w1, w3);
        pfA4 = make_uint4(w0, w1, w2, w3);
      }
      // ---- PV for both tiles (shared vf) ----
      {
        union { uint4 u4; bf16x8 v; } puB, puA;
        puB.u4 = pfB4; puA.u4 = pfA4;
        __builtin_amdgcn_s_setprio(1);
        #pragma unroll
        for (int j = 0; j < 4; j++)
          OB[j] = __builtin_amdgcn_mfma_f32_16x16x32_bf16(vf03[j], puB.v, OB[j], 0, 0, 0);
        if (doA) {
          #pragma unroll
          for (int j = 0; j < 4; j++)
            OA[j] = __builtin_amdgcn_mfma_f32_16x16x32_bf16(vf03[j], puA.v, OA[j], 0, 0, 0);
        }
        #pragma unroll
        for (int j = 0; j < 4; j++)
          OB[4 + j] = __builtin_amdgcn_mfma_f32_16x16x32_bf16(vf47[j], puB.v, OB[4 + j], 0, 0, 0);
        if (doA) {
          #pragma unroll
          for (int j = 0; j < 4; j++)
            OA[4 + j] = __builtin_amdgcn_mfma_f32_16x16x32_bf16(vf47[j], puA.v, OA[4 + j], 0, 0, 0);
        }
        __builtin_amdgcn_s_setprio(0);
      }
    }
    __syncthreads();                          // drains gllds vmcnt for next buffer
  }

  float* OpA = Opart + (size_t)slotA * (64 * 128) + (size_t)(wave*16 + col) * 128 + quad * 4;
  float* OpB = Opart + (size_t)slotB * (64 * 128) + (size_t)(wave*16 + col) * 128 + quad * 4;
  #pragma unroll
  for (int d = 0; d < 8; d++) {
    *(f32x4*)(OpA + d * 16) = OA[d];
    *(f32x4*)(OpB + d * 16) = OB[d];
  }
  if (quad == 0) {
    *(float2*)(ml + (size_t)slotA * 128 + (size_t)(wave*16 + col) * 2) = make_float2(mA, lA);
    *(float2*)(ml + (size_t)slotB * 128 + (size_t)(wave*16 + col) * 2) = make_float2(mB, lB);
  }
}

// ---------- kernel 5: combine split-K partials ----------
__global__ __launch_bounds__(256) void combine_kernel(const float* __restrict__ Opart,
    const float* __restrict__ ml, float* __restrict__ out) {
  const float SL2E = 0.08838834764831845f * 1.44269504088896340736f;
  int tile = blockIdx.x, b = blockIdx.y;
  int a = tile >> 3, rr = tile & 7;
  int nc = a + 1;
  int base = b * 288 + (a + 1) * (4 * a + rr);
  int tid = threadIdx.x;
  int row = tid >> 2;
  int cs = (tid & 3) * 4;
  float m_c[8], l_c[8];
  float mstar = -1e30f;
  for (int ci = 0; ci < nc; ci++) {
    m_c[ci] = ml[(size_t)(base + ci) * 128 + row * 2];
    l_c[ci] = ml[(size_t)(base + ci) * 128 + row * 2 + 1];
    mstar = fmaxf(mstar, m_c[ci]);
  }
  float denom = 0.f;
  float w_c[8];
  for (int ci = 0; ci < nc; ci++) {
    w_c[ci] = exp2f((m_c[ci] - mstar) * SL2E);
    denom += w_c[ci] * l_c[ci];
  }
  float inv = 1.f / denom;
  f32x4 acc[8];
  #pragma unroll
  for (int i = 0; i < 8; i++) acc[i] = (f32x4){0.f,0.f,0.f,0.f};
  for (int ci = 0; ci < nc; ci++) {
    const float* Op = Opart + (size_t)(base + ci) * (64 * 128) + row * 128;
    float w = w_c[ci];
    #pragma unroll
    for (int i = 0; i < 8; i++) {
      f32x4 v = *(const f32x4*)(Op + cs + i * 16);
      acc[i] += w * v;
    }
  }
  float* o = out + ((size_t)(b * S_) + tile * 64 + row) * H_;
  #pragma unroll
  for (int i = 0; i < 8; i++) {
    f32x4 v = acc[i] * inv;
    *(f32x4*)(o + cs + i * 16) = v;
  }
}

extern "C" void kernel_launch(void* const* d_in, const int* in_sizes, int n_in,
                              void* d_out, int out_size, void* d_ws, size_t ws_size,
                              hipStream_t stream) {
  (void)in_sizes; (void)n_in; (void)out_size; (void)ws_size;
  const float* x  = (const float*)d_in[0];
  const float* Wq = (const float*)d_in[1];
  const float* Wk = (const float*)d_in[2];
  const float* Wv = (const float*)d_in[3];
  float* out = (float*)d_out;
  char* ws = (char*)d_ws;
  ushort* Wt = (ushort*)ws;                                        // 768 KB
  ushort* qb = (ushort*)(ws + 786432);                             // 4 MB each
  ushort* kb = qb + (size_t)M_ * H_;
  ushort* vT = kb + (size_t)M_ * H_;
  float* Opart = (float*)(ws + 786432 + 3 * (size_t)M_ * H_ * 2);  // 36 MB
  float* ml = Opart + (size_t)1152 * 64 * 128;                     // 0.6 MB
  ushort* xbuf = (ushort*)Opart;   // alias: xb dead before flash writes Opart

  hipLaunchKernelGGL(wt_kernel,   dim3(384), dim3(256), 0, stream, Wq, Wk, Wv, Wt);
  hipLaunchKernelGGL(xb_kernel,   dim3(8192), dim3(256), 0, stream, x, xbuf);
  hipLaunchKernelGGL(qkv_gemm,    dim3(128, 3), dim3(256), 0, stream, xbuf, Wt, qb, kb, vT);
  hipLaunchKernelGGL(flash_kernel,dim3(8, 32, 4), dim3(256), 0, stream, qb, kb, vT, Opart, ml);
  hipLaunchKernelGGL(combine_kernel, dim3(64, 4), dim3(256), 0, stream, Opart, ml, out);
}

// Round 11
// 201.483 us; speedup vs baseline: 1.0659x; 1.0414x over previous
//
#include <hip/hip_runtime.h>

#define B_ 4
#define S_ 4096
#define E_ 1024
#define H_ 128
#define M_ (B_*S_)   // 16384

typedef __attribute__((ext_vector_type(8))) short bf16x8;
typedef __attribute__((ext_vector_type(4))) float f32x4;
typedef __attribute__((ext_vector_type(2))) unsigned int uint2v;

__device__ inline ushort f2bf(float f) {
  union { float f; unsigned u; } v; v.f = f;
  unsigned r = v.u + 0x7fffu + ((v.u >> 16) & 1u);   // RNE
  return (ushort)(r >> 16);
}
__device__ inline ushort f2h(float f) {              // f32 -> f16 bits (RNE)
  union { _Float16 h; ushort u; } v; v.h = (_Float16)f; return v.u;
}
__device__ inline float h2f(ushort u) {
  union { ushort u; _Float16 h; } v; v.u = u; return (float)v.h;
}

// ---- gfx950 cross-lane primitives ----
__device__ inline void pl16sw(unsigned &x, unsigned &y) {
#if __has_builtin(__builtin_amdgcn_permlane16_swap)
  uint2v r = __builtin_amdgcn_permlane16_swap(x, y, false, false);
  x = r.x; y = r.y;
#else
  asm("v_permlane16_swap_b32 %0, %1" : "+v"(x), "+v"(y));
#endif
}
__device__ inline void pl32sw(unsigned &x, unsigned &y) {
#if __has_builtin(__builtin_amdgcn_permlane32_swap)
  uint2v r = __builtin_amdgcn_permlane32_swap(x, y, false, false);
  x = r.x; y = r.y;
#else
  asm("v_permlane32_swap_b32 %0, %1" : "+v"(x), "+v"(y));
#endif
}
__device__ inline float red4max(float v) {
  union { float f; unsigned u; } a, b;
  a.f = v; b.f = v; pl16sw(a.u, b.u);
  float m1 = fmaxf(a.f, b.f);
  a.f = m1; b.f = m1; pl32sw(a.u, b.u);
  return fmaxf(a.f, b.f);
}
__device__ inline float red4sum(float v) {
  union { float f; unsigned u; } a, b;
  a.f = v; b.f = v; pl16sw(a.u, b.u);
  float s1 = a.f + b.f;
  a.f = s1; b.f = s1; pl32sw(a.u, b.u);
  return a.f + b.f;
}
__device__ inline unsigned cvt_pk_bf16(float lo, float hi) {
  unsigned w;
  asm("v_cvt_pk_bf16_f32 %0, %1, %2" : "=v"(w) : "v"(lo), "v"(hi));
  return w;
}

#define GLLDS16(g, l) __builtin_amdgcn_global_load_lds( \
    (const __attribute__((address_space(1))) void*)(g), \
    (__attribute__((address_space(3))) void*)(l), 16, 0, 0)

// ---------- kernel 1: W [1024][128] f32 (x3) -> Wt [3][128][1024] bf16 ----------
__global__ __launch_bounds__(256) void wt_kernel(const float* __restrict__ Wq,
    const float* __restrict__ Wk, const float* __restrict__ Wv,
    ushort* __restrict__ Wt) {
  int bid = blockIdx.x;               // 384 = 3 mats * 4 h-tiles * 32 e-tiles
  int mat = bid >> 7;
  int rem = bid & 127;
  int ht = rem >> 5, et = rem & 31;
  const float* W = mat == 0 ? Wq : (mat == 1 ? Wk : Wv);
  int e0 = et * 32, h0 = ht * 32;
  __shared__ float tl[32][33];
  int t = threadIdx.x;
  int r = t >> 3, c = (t & 7) << 2;
  const float4 f = *(const float4*)(W + (size_t)(e0 + r) * H_ + h0 + c);
  tl[r][c] = f.x; tl[r][c+1] = f.y; tl[r][c+2] = f.z; tl[r][c+3] = f.w;
  __syncthreads();
  ushort4 o;
  o.x = f2bf(tl[c+0][r]); o.y = f2bf(tl[c+1][r]);
  o.z = f2bf(tl[c+2][r]); o.w = f2bf(tl[c+3][r]);
  *(ushort4*)(Wt + ((size_t)mat*H_ + h0 + r) * E_ + e0 + c) = o;
}

// ---------- kernel 2: x f32 -> bf16 (memory-bound) ----------
__global__ __launch_bounds__(256) void xb_kernel(const float* __restrict__ x,
                                                 ushort* __restrict__ xb) {
  size_t i = ((size_t)blockIdx.x * 256 + threadIdx.x) * 8;
  float4 f0 = *(const float4*)(x + i);
  float4 f1 = *(const float4*)(x + i + 4);
  alignas(16) ushort us[8];
  us[0]=f2bf(f0.x); us[1]=f2bf(f0.y); us[2]=f2bf(f0.z); us[3]=f2bf(f0.w);
  us[4]=f2bf(f1.x); us[5]=f2bf(f1.y); us[6]=f2bf(f1.z); us[7]=f2bf(f1.w);
  *(uint4*)(xb + i) = *(uint4*)&us[0];
}

// ---------- kernel 3: QKV GEMM (V epilogue writes tiled [g=key/32][dim][key&31]) ----------
__global__ __launch_bounds__(256, 2) void qkv_gemm(const ushort* __restrict__ xb,
    const ushort* __restrict__ Wt, ushort* __restrict__ qo,
    ushort* __restrict__ ko, ushort* __restrict__ vTo) {
  const int m0 = blockIdx.x * 128;
  const int mat = blockIdx.y;
  const ushort* Bsrc = Wt + (size_t)mat * H_ * E_;
  __shared__ ushort As[2][128 * 64];
  __shared__ ushort Bs[2][128 * 64];
  const int tid = threadIdx.x;
  const int wave = tid >> 6, lane = tid & 63;
  const int col = lane & 15, quad = lane >> 4;
  const int wr = wave >> 1, wc = wave & 1;

  f32x4 acc[4][4];
  #pragma unroll
  for (int i = 0; i < 4; i++)
    #pragma unroll
    for (int j = 0; j < 4; j++) acc[i][j] = (f32x4){0.f,0.f,0.f,0.f};

  const int srow = lane >> 3;
  const int sunit = (lane & 7) ^ srow;
  const int gcol = sunit * 8;

  #define STAGE_QKV(it, bufi) do { \
    _Pragma("unroll") \
    for (int j = 0; j < 4; j++) { \
      int rbase = wave*8 + j*32; \
      GLLDS16(xb + (size_t)(m0 + rbase + srow) * E_ + (it)*64 + gcol, \
              &As[bufi][rbase * 64]); \
      GLLDS16(Bsrc + (size_t)(rbase + srow) * E_ + (it)*64 + gcol, \
              &Bs[bufi][rbase * 64]); \
    } \
  } while (0)

  STAGE_QKV(0, 0);
  __syncthreads();

  for (int it = 0; it < 16; it++) {
    if (it < 15) STAGE_QKV(it + 1, (it + 1) & 1);
    const ushort* a = &As[it & 1][0];
    const ushort* bb = &Bs[it & 1][0];
    #pragma unroll
    for (int kc = 0; kc < 2; kc++) {
      bf16x8 af[4], bf[4];
      #pragma unroll
      for (int mi = 0; mi < 4; mi++) {
        int rr = wr*64 + mi*16 + col;
        af[mi] = *(const bf16x8*)(a + rr*64 + (((kc*4 + quad) ^ (col & 7)) * 8));
      }
      #pragma unroll
      for (int ni = 0; ni < 4; ni++) {
        int rr = wc*64 + ni*16 + col;
        bf[ni] = *(const bf16x8*)(bb + rr*64 + (((kc*4 + quad) ^ (col & 7)) * 8));
      }
      #pragma unroll
      for (int mi = 0; mi < 4; mi++)
        #pragma unroll
        for (int ni = 0; ni < 4; ni++)
          acc[mi][ni] = __builtin_amdgcn_mfma_f32_16x16x32_bf16(af[mi], bf[ni], acc[mi][ni], 0, 0, 0);
    }
    __syncthreads();
  }

  if (mat == 2) {
    int bb = m0 >> 12;
    int sbase = (m0 & 4095) + wr * 64;
    #pragma unroll
    for (int ni = 0; ni < 4; ni++) {
      int n = wc*64 + ni*16 + col;
      #pragma unroll
      for (int mi = 0; mi < 4; mi++) {
        int s = sbase + mi*16 + quad*4;
        ushort4 o;
        o.x = f2bf(acc[mi][ni][0]); o.y = f2bf(acc[mi][ni][1]);
        o.z = f2bf(acc[mi][ni][2]); o.w = f2bf(acc[mi][ni][3]);
        *(ushort4*)(vTo + ((size_t)(bb * 128 + (s >> 5)) * 128 + n) * 32 + (s & 31)) = o;
      }
    }
  } else {
    ushort* dst = (mat == 0 ? qo : ko);
    #pragma unroll
    for (int ni = 0; ni < 4; ni++) {
      int n = wc*64 + ni*16 + col;
      #pragma unroll
      for (int mi = 0; mi < 4; mi++) {
        int row = m0 + wr*64 + mi*16 + quad*4;
        #pragma unroll
        for (int r = 0; r < 4; r++)
          dst[(size_t)(row + r) * H_ + n] = f2bf(acc[mi][ni][r]);
      }
    }
  }
}

// ---------- kernel 4: causal flash, tile-PAIR per WG, CHUNK=512, gllds K+V ----------
// R11 vs R10: (a) V LDS bank-conflict fix -- R10's linear V gave 8-way conflicts
// (1.07M counted: lanes at 64B row stride -> banks {0,16}). Source-side XOR swizzle
// (rule #21, both sides): stage global unit u^((d>>1)&3) into linear unit u; read
// unit quad^((col>>1)&3). Lanes now span 8 banks x 2 = 2-way = free (m136).
// (b) f16 Opart partials (R9-proven numerics) -> WRITE_SIZE and combine reads halved.
#define CHUNK_ 512
__global__ __launch_bounds__(256, 2) void flash_kernel(const ushort* __restrict__ q,
    const ushort* __restrict__ k, const ushort* __restrict__ vT,
    ushort* __restrict__ Opart, float* __restrict__ ml) {
  const float SL2E = 0.08838834764831845f * 1.44269504088896340736f;
  int c = blockIdx.x;
  int tp = 31 - (int)blockIdx.y;              // heavy pairs first
  int b = blockIdx.z;
  if (tp < 4 * c) return;
  int tA = tp * 2, tB = tA + 1;
  int aA = tA >> 3, rA = tA & 7;
  int aB = tB >> 3, rB = tB & 7;
  int slotA = b * 288 + (aA + 1) * (4 * aA + rA) + c;
  int slotB = b * 288 + (aB + 1) * (4 * aB + rB) + c;

  int wave = threadIdx.x >> 6, lane = threadIdx.x & 63;
  int col = lane & 15, quad = lane >> 4;
  int q0A = tA * 64 + wave * 16;
  int q0B = q0A + 64;
  const ushort* qb = q + (size_t)b * S_ * H_;
  const ushort* kbp = k + (size_t)b * S_ * H_;
  const ushort* vb = vT + (size_t)b * S_ * H_;

  __shared__ ushort kl[2][32 * 128];          // K double-buffer (16 KB), src-side swizzle
  __shared__ ushort vl[2][32 * 128];          // V double-buffer (16 KB), src-side swizzle

  bf16x8 qfA[4], qfB[4];
  {
    const ushort* qpA = qb + (size_t)(q0A + col) * H_ + quad * 8;
    const ushort* qpB = qb + (size_t)(q0B + col) * H_ + quad * 8;
    #pragma unroll
    for (int kc = 0; kc < 4; kc++) {
      qfA[kc] = *(const bf16x8*)(qpA + kc * 32);
      qfB[kc] = *(const bf16x8*)(qpB + kc * 32);
    }
  }

  f32x4 OA[8], OB[8];
  #pragma unroll
  for (int d = 0; d < 8; d++) { OA[d] = (f32x4){0.f,0.f,0.f,0.f}; OB[d] = (f32x4){0.f,0.f,0.f,0.f}; }
  float mA = -1e30f, lA = 0.f, mB = -1e30f, lB = 0.f;

  const int c0 = c * CHUNK_;
  const int kendWG = min(c0 + CHUNK_, tB * 64 + 64);
  const int nblk = (kendWG - c0 + 31) >> 5;
  const int qlimA = q0A + 15, qlimB = q0B + 15;

  const int sk0 = wave * 8 + quad;            // staged K rows sk0 and sk0+4
  const int gu0 = (col ^ (sk0 & 15)) * 8;     // K: pre-swizzled global src unit
  const int gu1 = (col ^ ((sk0 + 4) & 15)) * 8;
  // V source (swizzled): thread covers dim d = wave*32 + (lane>>2) (+16 for 2nd call),
  // LDS unit u = lane&3 holds global unit u ^ ((d>>1)&3); (d>>1)&3 == (lane>>3)&3.
  const ushort* vsrc = vb + (size_t)c * 16 * 4096 + (size_t)wave * 1024
                     + (lane >> 2) * 32 + (((lane & 3) ^ ((lane >> 3) & 3)) * 8);
  // V read unit (swizzled): quad ^ ((col>>1)&3), constant across j (16-dim steps).
  const int vru = ((quad ^ ((col >> 1) & 3)) * 8);

  #define STAGE_KV(kb, g, bufi) do { \
    GLLDS16(kbp + (size_t)((kb) + sk0) * H_ + gu0,     &kl[bufi][wave * 1024]); \
    GLLDS16(kbp + (size_t)((kb) + sk0 + 4) * H_ + gu1, &kl[bufi][wave * 1024 + 512]); \
    GLLDS16(vsrc + (size_t)(g) * 4096,                 &vl[bufi][wave * 1024]); \
    GLLDS16(vsrc + (size_t)(g) * 4096 + 512,           &vl[bufi][wave * 1024 + 512]); \
  } while (0)

  STAGE_KV(c0, 0, 0);
  __syncthreads();

  for (int ib = 0; ib < nblk; ib++) {
    const int kb0 = c0 + ib * 32;
    if (ib + 1 < nblk) STAGE_KV(kb0 + 32, ib + 1, (ib + 1) & 1);  // T14: drained at barrier
    if (kb0 <= qlimB) {                       // wave-uniform
      const bool doA = (kb0 <= qlimA);
      const ushort* kcur = &kl[ib & 1][0];
      const ushort* vcur = &vl[ib & 1][0];
      // K fragments from LDS
      bf16x8 kf0[4], kf1[4];
      #pragma unroll
      for (int kc = 0; kc < 4; kc++) {
        int u = quad + kc * 4;
        kf0[kc] = *(const bf16x8*)(kcur + col*128        + ((u ^ col) * 8));
        kf1[kc] = *(const bf16x8*)(kcur + (16 + col)*128 + ((u ^ col) * 8));
      }
      // QK^T
      f32x4 sB0 = (f32x4){0.f,0.f,0.f,0.f}, sB1 = sB0, sA0 = sB0, sA1 = sB0;
      __builtin_amdgcn_s_setprio(1);
      #pragma unroll
      for (int kc = 0; kc < 4; kc++) {
        sB0 = __builtin_amdgcn_mfma_f32_16x16x32_bf16(kf0[kc], qfB[kc], sB0, 0, 0, 0);
        sB1 = __builtin_amdgcn_mfma_f32_16x16x32_bf16(kf1[kc], qfB[kc], sB1, 0, 0, 0);
      }
      if (doA) {
        #pragma unroll
        for (int kc = 0; kc < 4; kc++) {
          sA0 = __builtin_amdgcn_mfma_f32_16x16x32_bf16(kf0[kc], qfA[kc], sA0, 0, 0, 0);
          sA1 = __builtin_amdgcn_mfma_f32_16x16x32_bf16(kf1[kc], qfA[kc], sA1, 0, 0, 0);
        }
      }
      __builtin_amdgcn_s_setprio(0);
      // V fragments 0..3 from LDS (swizzled unit; overlap softmax B)
      bf16x8 vf03[4];
      #pragma unroll
      for (int j = 0; j < 4; j++)
        vf03[j] = *(const bf16x8*)(vcur + col * 32 + j * 512 + vru);
      // ---- tile B softmax ----
      uint4 pfB4;
      {
        float s[8];
        #pragma unroll
        for (int r = 0; r < 4; r++) { s[r] = sB0[r]; s[4+r] = sB1[r]; }
        if (kb0 + 31 > q0B) {
          #pragma unroll
          for (int r = 0; r < 4; r++) {
            if (kb0 + quad*4 + r      > q0B + col) s[r]   = -1e30f;
            if (kb0 + 16 + quad*4 + r > q0B + col) s[4+r] = -1e30f;
          }
        }
        float cm = s[0];
        #pragma unroll
        for (int j = 1; j < 8; j++) cm = fmaxf(cm, s[j]);
        cm = red4max(cm);
        if (!__all(cm <= mB)) {               // T13 exact skip
          float mn = fmaxf(mB, cm);
          float alpha = exp2f((mB - mn) * SL2E);
          lB *= alpha;
          #pragma unroll
          for (int d = 0; d < 8; d++) OB[d] *= alpha;
          mB = mn;
        }
        float rs = 0.f;
        #pragma unroll
        for (int j = 0; j < 8; j++) { s[j] = exp2f((s[j] - mB) * SL2E); rs += s[j]; }
        lB += red4sum(rs);
        unsigned w0 = cvt_pk_bf16(s[0], s[1]);
        unsigned w1 = cvt_pk_bf16(s[2], s[3]);
        unsigned w2 = cvt_pk_bf16(s[4], s[5]);
        unsigned w3 = cvt_pk_bf16(s[6], s[7]);
        pl32sw(w0, w2); pl32sw(w1, w3);
        pl16sw(w0, w2); pl16sw(w1, w3);
        pfB4 = make_uint4(w0, w1, w2, w3);
      }
      // V fragments 4..7 (overlap softmax A)
      bf16x8 vf47[4];
      #pragma unroll
      for (int j = 0; j < 4; j++)
        vf47[j] = *(const bf16x8*)(vcur + col * 32 + (4 + j) * 512 + vru);
      // ---- tile A softmax ----
      uint4 pfA4 = make_uint4(0u, 0u, 0u, 0u);
      if (doA) {
        float s[8];
        #pragma unroll
        for (int r = 0; r < 4; r++) { s[r] = sA0[r]; s[4+r] = sA1[r]; }
        if (kb0 + 31 > q0A) {
          #pragma unroll
          for (int r = 0; r < 4; r++) {
            if (kb0 + quad*4 + r      > q0A + col) s[r]   = -1e30f;
            if (kb0 + 16 + quad*4 + r > q0A + col) s[4+r] = -1e30f;
          }
        }
        float cm = s[0];
        #pragma unroll
        for (int j = 1; j < 8; j++) cm = fmaxf(cm, s[j]);
        cm = red4max(cm);
        if (!__all(cm <= mA)) {
          float mn = fmaxf(mA, cm);
          float alpha = exp2f((mA - mn) * SL2E);
          lA *= alpha;
          #pragma unroll
          for (int d = 0; d < 8; d++) OA[d] *= alpha;
          mA = mn;
        }
        float rs = 0.f;
        #pragma unroll
        for (int j = 0; j < 8; j++) { s[j] = exp2f((s[j] - mA) * SL2E); rs += s[j]; }
        lA += red4sum(rs);
        unsigned w0 = cvt_pk_bf16(s[0], s[1]);
        unsigned w1 = cvt_pk_bf16(s[2], s[3]);
        unsigned w2 = cvt_pk_bf16(s[4], s[5]);
        unsigned w3 = cvt_pk_bf16(s[6], s[7]);
        pl32sw(w0, w2); pl32sw(w1, w3);
        pl16sw(w0, w2); pl16sw(w1, w3);
        pfA4 = make_uint4(w0, w1, w2, w3);
      }
      // ---- PV for both tiles (shared vf) ----
      {
        union { uint4 u4; bf16x8 v; } puB, puA;
        puB.u4 = pfB4; puA.u4 = pfA4;
        __builtin_amdgcn_s_setprio(1);
        #pragma unroll
        for (int j = 0; j < 4; j++)
          OB[j] = __builtin_amdgcn_mfma_f32_16x16x32_bf16(vf03[j], puB.v, OB[j], 0, 0, 0);
        if (doA) {
          #pragma unroll
          for (int j = 0; j < 4; j++)
            OA[j] = __builtin_amdgcn_mfma_f32_16x16x32_bf16(vf03[j], puA.v, OA[j], 0, 0, 0);
        }
        #pragma unroll
        for (int j = 0; j < 4; j++)
          OB[4 + j] = __builtin_amdgcn_mfma_f32_16x16x32_bf16(vf47[j], puB.v, OB[4 + j], 0, 0, 0);
        if (doA) {
          #pragma unroll
          for (int j = 0; j < 4; j++)
            OA[4 + j] = __builtin_amdgcn_mfma_f32_16x16x32_bf16(vf47[j], puA.v, OA[4 + j], 0, 0, 0);
        }
        __builtin_amdgcn_s_setprio(0);
      }
    }
    __syncthreads();                          // drains gllds vmcnt for next buffer
  }

  // f16 partial epilogue
  ushort* OpA = Opart + (size_t)slotA * (64 * 128) + (size_t)(wave*16 + col) * 128 + quad * 4;
  ushort* OpB = Opart + (size_t)slotB * (64 * 128) + (size_t)(wave*16 + col) * 128 + quad * 4;
  #pragma unroll
  for (int d = 0; d < 8; d++) {
    ushort4 ha, hb;
    ha.x = f2h(OA[d][0]); ha.y = f2h(OA[d][1]); ha.z = f2h(OA[d][2]); ha.w = f2h(OA[d][3]);
    hb.x = f2h(OB[d][0]); hb.y = f2h(OB[d][1]); hb.z = f2h(OB[d][2]); hb.w = f2h(OB[d][3]);
    *(ushort4*)(OpA + d * 16) = ha;
    *(ushort4*)(OpB + d * 16) = hb;
  }
  if (quad == 0) {
    *(float2*)(ml + (size_t)slotA * 128 + (size_t)(wave*16 + col) * 2) = make_float2(mA, lA);
    *(float2*)(ml + (size_t)slotB * 128 + (size_t)(wave*16 + col) * 2) = make_float2(mB, lB);
  }
}

// ---------- kernel 5: combine split-K partials (f16, two-pass, no local arrays) ----------
__global__ __launch_bounds__(256) void combine_kernel(const ushort* __restrict__ Opart,
    const float* __restrict__ ml, float* __restrict__ out) {
  const float SL2E = 0.08838834764831845f * 1.44269504088896340736f;
  int tile = blockIdx.x, b = blockIdx.y;
  int a = tile >> 3, rr = tile & 7;
  int nc = a + 1;
  int base = b * 288 + (a + 1) * (4 * a + rr);
  int tid = threadIdx.x;
  int row = tid >> 2;
  int cs = (tid & 3) * 4;
  // pass 1: global max (no local arrays -> no scratch; rule #20)
  float mstar = -1e30f;
  for (int ci = 0; ci < nc; ci++)
    mstar = fmaxf(mstar, ml[(size_t)(base + ci) * 128 + row * 2]);
  // pass 2: weighted accumulate
  float denom = 0.f;
  f32x4 acc[8];
  #pragma unroll
  for (int i = 0; i < 8; i++) acc[i] = (f32x4){0.f,0.f,0.f,0.f};
  for (int ci = 0; ci < nc; ci++) {
    float mc = ml[(size_t)(base + ci) * 128 + row * 2];
    float lc = ml[(size_t)(base + ci) * 128 + row * 2 + 1];
    float w = exp2f((mc - mstar) * SL2E);
    denom += w * lc;
    const ushort* Op = Opart + (size_t)(base + ci) * (64 * 128) + row * 128;
    #pragma unroll
    for (int i = 0; i < 8; i++) {
      ushort4 h = *(const ushort4*)(Op + cs + i * 16);
      acc[i][0] += w * h2f(h.x);
      acc[i][1] += w * h2f(h.y);
      acc[i][2] += w * h2f(h.z);
      acc[i][3] += w * h2f(h.w);
    }
  }
  float inv = 1.f / denom;
  float* o = out + ((size_t)(b * S_) + tile * 64 + row) * H_;
  #pragma unroll
  for (int i = 0; i < 8; i++) {
    f32x4 v = acc[i] * inv;
    *(f32x4*)(o + cs + i * 16) = v;
  }
}

extern "C" void kernel_launch(void* const* d_in, const int* in_sizes, int n_in,
                              void* d_out, int out_size, void* d_ws, size_t ws_size,
                              hipStream_t stream) {
  (void)in_sizes; (void)n_in; (void)out_size; (void)ws_size;
  const float* x  = (const float*)d_in[0];
  const float* Wq = (const float*)d_in[1];
  const float* Wk = (const float*)d_in[2];
  const float* Wv = (const float*)d_in[3];
  float* out = (float*)d_out;
  char* ws = (char*)d_ws;
  ushort* Wt = (ushort*)ws;                                        // 768 KB
  ushort* qb = (ushort*)(ws + 786432);                             // 4 MB each
  ushort* kb = qb + (size_t)M_ * H_;
  ushort* vT = kb + (size_t)M_ * H_;
  // Opart region aliased with xbuf (32 MB needed for xbuf > 18.9 MB f16 Opart)
  ushort* Opart = (ushort*)(ws + 786432 + 3 * (size_t)M_ * H_ * 2);
  float* ml = (float*)((char*)Opart + (size_t)M_ * E_ * 2);        // after 32 MB alias region
  ushort* xbuf = Opart;            // alias: xb dead before flash writes Opart

  hipLaunchKernelGGL(wt_kernel,   dim3(384), dim3(256), 0, stream, Wq, Wk, Wv, Wt);
  hipLaunchKernelGGL(xb_kernel,   dim3(8192), dim3(256), 0, stream, x, xbuf);
  hipLaunchKernelGGL(qkv_gemm,    dim3(128, 3), dim3(256), 0, stream, xbuf, Wt, qb, kb, vT);
  hipLaunchKernelGGL(flash_kernel,dim3(8, 32, 4), dim3(256), 0, stream, qb, kb, vT, Opart, ml);
  hipLaunchKernelGGL(combine_kernel, dim3(64, 4), dim3(256), 0, stream, Opart, ml, out);
}

// Round 12
// 201.162 us; speedup vs baseline: 1.0676x; 1.0016x over previous
//
#include <hip/hip_runtime.h>

#define B_ 4
#define S_ 4096
#define E_ 1024
#define H_ 128
#define M_ (B_*S_)   // 16384

typedef __attribute__((ext_vector_type(8))) short bf16x8;
typedef __attribute__((ext_vector_type(4))) float f32x4;
typedef __attribute__((ext_vector_type(2))) unsigned int uint2v;

__device__ inline ushort f2bf(float f) {
  union { float f; unsigned u; } v; v.f = f;
  unsigned r = v.u + 0x7fffu + ((v.u >> 16) & 1u);   // RNE
  return (ushort)(r >> 16);
}
__device__ inline ushort f2h(float f) {              // f32 -> f16 bits (RNE)
  union { _Float16 h; ushort u; } v; v.h = (_Float16)f; return v.u;
}
__device__ inline float h2f(ushort u) {
  union { ushort u; _Float16 h; } v; v.u = u; return (float)v.h;
}

// ---- gfx950 cross-lane primitives ----
__device__ inline void pl16sw(unsigned &x, unsigned &y) {
#if __has_builtin(__builtin_amdgcn_permlane16_swap)
  uint2v r = __builtin_amdgcn_permlane16_swap(x, y, false, false);
  x = r.x; y = r.y;
#else
  asm("v_permlane16_swap_b32 %0, %1" : "+v"(x), "+v"(y));
#endif
}
__device__ inline void pl32sw(unsigned &x, unsigned &y) {
#if __has_builtin(__builtin_amdgcn_permlane32_swap)
  uint2v r = __builtin_amdgcn_permlane32_swap(x, y, false, false);
  x = r.x; y = r.y;
#else
  asm("v_permlane32_swap_b32 %0, %1" : "+v"(x), "+v"(y));
#endif
}
__device__ inline float red4max(float v) {
  union { float f; unsigned u; } a, b;
  a.f = v; b.f = v; pl16sw(a.u, b.u);
  float m1 = fmaxf(a.f, b.f);
  a.f = m1; b.f = m1; pl32sw(a.u, b.u);
  return fmaxf(a.f, b.f);
}
__device__ inline float red4sum(float v) {
  union { float f; unsigned u; } a, b;
  a.f = v; b.f = v; pl16sw(a.u, b.u);
  float s1 = a.f + b.f;
  a.f = s1; b.f = s1; pl32sw(a.u, b.u);
  return a.f + b.f;
}
__device__ inline unsigned cvt_pk_bf16(float lo, float hi) {
  unsigned w;
  asm("v_cvt_pk_bf16_f32 %0, %1, %2" : "=v"(w) : "v"(lo), "v"(hi));
  return w;
}

#define GLLDS16(g, l) __builtin_amdgcn_global_load_lds( \
    (const __attribute__((address_space(1))) void*)(g), \
    (__attribute__((address_space(3))) void*)(l), 16, 0, 0)

// ---------- kernel 1: W [1024][128] f32 (x3) -> Wt [3][128][1024] bf16 ----------
__global__ __launch_bounds__(256) void wt_kernel(const float* __restrict__ Wq,
    const float* __restrict__ Wk, const float* __restrict__ Wv,
    ushort* __restrict__ Wt) {
  int bid = blockIdx.x;               // 384 = 3 mats * 4 h-tiles * 32 e-tiles
  int mat = bid >> 7;
  int rem = bid & 127;
  int ht = rem >> 5, et = rem & 31;
  const float* W = mat == 0 ? Wq : (mat == 1 ? Wk : Wv);
  int e0 = et * 32, h0 = ht * 32;
  __shared__ float tl[32][33];
  int t = threadIdx.x;
  int r = t >> 3, c = (t & 7) << 2;
  const float4 f = *(const float4*)(W + (size_t)(e0 + r) * H_ + h0 + c);
  tl[r][c] = f.x; tl[r][c+1] = f.y; tl[r][c+2] = f.z; tl[r][c+3] = f.w;
  __syncthreads();
  ushort4 o;
  o.x = f2bf(tl[c+0][r]); o.y = f2bf(tl[c+1][r]);
  o.z = f2bf(tl[c+2][r]); o.w = f2bf(tl[c+3][r]);
  *(ushort4*)(Wt + ((size_t)mat*H_ + h0 + r) * E_ + e0 + c) = o;
}

// ---------- kernel 2: QKV GEMM, FUSED x f32->bf16 conversion in A-staging ----------
// R12: xb_kernel (96 MB round trip, ~15us) deleted. A-tiles reg-staged from x f32,
// converted with v_cvt_pk_bf16_f32 (RNE, 4 instr / 8 elems), written via wave-linear
// ds_write_b128 (lane l -> byte l*16 == the exact layout gllds produced; MFMA read
// side unchanged). T14: loads at iteration top, convert+write after MFMA, before
// barrier. B (Wt bf16) stays on gllds. x read 3x (64 MB, L3-resident after pass 1).
__global__ __launch_bounds__(256, 2) void qkv_gemm(const float* __restrict__ x,
    const ushort* __restrict__ Wt, ushort* __restrict__ qo,
    ushort* __restrict__ ko, ushort* __restrict__ vTo) {
  const int m0 = blockIdx.x * 128;
  const int mat = blockIdx.y;
  const ushort* Bsrc = Wt + (size_t)mat * H_ * E_;
  __shared__ ushort As[2][128 * 64];
  __shared__ ushort Bs[2][128 * 64];
  const int tid = threadIdx.x;
  const int wave = tid >> 6, lane = tid & 63;
  const int col = lane & 15, quad = lane >> 4;
  const int wr = wave >> 1, wc = wave & 1;

  f32x4 acc[4][4];
  #pragma unroll
  for (int i = 0; i < 4; i++)
    #pragma unroll
    for (int j = 0; j < 4; j++) acc[i][j] = (f32x4){0.f,0.f,0.f,0.f};

  const int srow = lane >> 3;
  const int sunit = (lane & 7) ^ srow;
  const int gcol = sunit * 8;
  const int lwoff = (lane & 7) * 8;   // linear LDS unit for A ds_writes

  float4 fa[4][2];
  #define STAGE_A_LOAD(it) do { \
    _Pragma("unroll") \
    for (int j = 0; j < 4; j++) { \
      const float* xp = x + (size_t)(m0 + wave*8 + j*32 + srow) * E_ + (it)*64 + gcol; \
      fa[j][0] = *(const float4*)xp; \
      fa[j][1] = *(const float4*)(xp + 4); \
    } \
  } while (0)
  #define STAGE_A_WRITE(bufi) do { \
    _Pragma("unroll") \
    for (int j = 0; j < 4; j++) { \
      uint4 u = make_uint4(cvt_pk_bf16(fa[j][0].x, fa[j][0].y), \
                           cvt_pk_bf16(fa[j][0].z, fa[j][0].w), \
                           cvt_pk_bf16(fa[j][1].x, fa[j][1].y), \
                           cvt_pk_bf16(fa[j][1].z, fa[j][1].w)); \
      *(uint4*)(&As[bufi][(wave*8 + j*32 + srow) * 64 + lwoff]) = u; \
    } \
  } while (0)
  #define STAGE_B(it, bufi) do { \
    _Pragma("unroll") \
    for (int j = 0; j < 4; j++) { \
      int rbase = wave*8 + j*32; \
      GLLDS16(Bsrc + (size_t)(rbase + srow) * E_ + (it)*64 + gcol, \
              &Bs[bufi][rbase * 64]); \
    } \
  } while (0)

  STAGE_A_LOAD(0);
  STAGE_B(0, 0);
  STAGE_A_WRITE(0);
  __syncthreads();

  for (int it = 0; it < 16; it++) {
    if (it < 15) { STAGE_A_LOAD(it + 1); STAGE_B(it + 1, (it + 1) & 1); }
    const ushort* a = &As[it & 1][0];
    const ushort* bb = &Bs[it & 1][0];
    #pragma unroll
    for (int kc = 0; kc < 2; kc++) {
      bf16x8 af[4], bf[4];
      #pragma unroll
      for (int mi = 0; mi < 4; mi++) {
        int rr = wr*64 + mi*16 + col;
        af[mi] = *(const bf16x8*)(a + rr*64 + (((kc*4 + quad) ^ (col & 7)) * 8));
      }
      #pragma unroll
      for (int ni = 0; ni < 4; ni++) {
        int rr = wc*64 + ni*16 + col;
        bf[ni] = *(const bf16x8*)(bb + rr*64 + (((kc*4 + quad) ^ (col & 7)) * 8));
      }
      #pragma unroll
      for (int mi = 0; mi < 4; mi++)
        #pragma unroll
        for (int ni = 0; ni < 4; ni++)
          acc[mi][ni] = __builtin_amdgcn_mfma_f32_16x16x32_bf16(af[mi], bf[ni], acc[mi][ni], 0, 0, 0);
    }
    if (it < 15) STAGE_A_WRITE((it + 1) & 1);   // loads had MFMA-time to land
    __syncthreads();
  }

  if (mat == 2) {
    int bb = m0 >> 12;
    int sbase = (m0 & 4095) + wr * 64;
    #pragma unroll
    for (int ni = 0; ni < 4; ni++) {
      int n = wc*64 + ni*16 + col;
      #pragma unroll
      for (int mi = 0; mi < 4; mi++) {
        int s = sbase + mi*16 + quad*4;
        ushort4 o;
        o.x = f2bf(acc[mi][ni][0]); o.y = f2bf(acc[mi][ni][1]);
        o.z = f2bf(acc[mi][ni][2]); o.w = f2bf(acc[mi][ni][3]);
        *(ushort4*)(vTo + ((size_t)(bb * 128 + (s >> 5)) * 128 + n) * 32 + (s & 31)) = o;
      }
    }
  } else {
    ushort* dst = (mat == 0 ? qo : ko);
    #pragma unroll
    for (int ni = 0; ni < 4; ni++) {
      int n = wc*64 + ni*16 + col;
      #pragma unroll
      for (int mi = 0; mi < 4; mi++) {
        int row = m0 + wr*64 + mi*16 + quad*4;
        #pragma unroll
        for (int r = 0; r < 4; r++)
          dst[(size_t)(row + r) * H_ + n] = f2bf(acc[mi][ni][r]);
      }
    }
  }
}

// ---------- kernel 4: causal flash, tile-PAIR per WG, CHUNK=512, gllds K+V ----------
// == R11 (best flash config): V src-side XOR swizzle (conflicts 0), f16 partials.
#define CHUNK_ 512
__global__ __launch_bounds__(256, 2) void flash_kernel(const ushort* __restrict__ q,
    const ushort* __restrict__ k, const ushort* __restrict__ vT,
    ushort* __restrict__ Opart, float* __restrict__ ml) {
  const float SL2E = 0.08838834764831845f * 1.44269504088896340736f;
  int c = blockIdx.x;
  int tp = 31 - (int)blockIdx.y;              // heavy pairs first
  int b = blockIdx.z;
  if (tp < 4 * c) return;
  int tA = tp * 2, tB = tA + 1;
  int aA = tA >> 3, rA = tA & 7;
  int aB = tB >> 3, rB = tB & 7;
  int slotA = b * 288 + (aA + 1) * (4 * aA + rA) + c;
  int slotB = b * 288 + (aB + 1) * (4 * aB + rB) + c;

  int wave = threadIdx.x >> 6, lane = threadIdx.x & 63;
  int col = lane & 15, quad = lane >> 4;
  int q0A = tA * 64 + wave * 16;
  int q0B = q0A + 64;
  const ushort* qb = q + (size_t)b * S_ * H_;
  const ushort* kbp = k + (size_t)b * S_ * H_;
  const ushort* vb = vT + (size_t)b * S_ * H_;

  __shared__ ushort kl[2][32 * 128];          // K double-buffer (16 KB), src-side swizzle
  __shared__ ushort vl[2][32 * 128];          // V double-buffer (16 KB), src-side swizzle

  bf16x8 qfA[4], qfB[4];
  {
    const ushort* qpA = qb + (size_t)(q0A + col) * H_ + quad * 8;
    const ushort* qpB = qb + (size_t)(q0B + col) * H_ + quad * 8;
    #pragma unroll
    for (int kc = 0; kc < 4; kc++) {
      qfA[kc] = *(const bf16x8*)(qpA + kc * 32);
      qfB[kc] = *(const bf16x8*)(qpB + kc * 32);
    }
  }

  f32x4 OA[8], OB[8];
  #pragma unroll
  for (int d = 0; d < 8; d++) { OA[d] = (f32x4){0.f,0.f,0.f,0.f}; OB[d] = (f32x4){0.f,0.f,0.f,0.f}; }
  float mA = -1e30f, lA = 0.f, mB = -1e30f, lB = 0.f;

  const int c0 = c * CHUNK_;
  const int kendWG = min(c0 + CHUNK_, tB * 64 + 64);
  const int nblk = (kendWG - c0 + 31) >> 5;
  const int qlimA = q0A + 15, qlimB = q0B + 15;

  const int sk0 = wave * 8 + quad;            // staged K rows sk0 and sk0+4
  const int gu0 = (col ^ (sk0 & 15)) * 8;     // K: pre-swizzled global src unit
  const int gu1 = (col ^ ((sk0 + 4) & 15)) * 8;
  const ushort* vsrc = vb + (size_t)c * 16 * 4096 + (size_t)wave * 1024
                     + (lane >> 2) * 32 + (((lane & 3) ^ ((lane >> 3) & 3)) * 8);
  const int vru = ((quad ^ ((col >> 1) & 3)) * 8);

  #define STAGE_KV(kb, g, bufi) do { \
    GLLDS16(kbp + (size_t)((kb) + sk0) * H_ + gu0,     &kl[bufi][wave * 1024]); \
    GLLDS16(kbp + (size_t)((kb) + sk0 + 4) * H_ + gu1, &kl[bufi][wave * 1024 + 512]); \
    GLLDS16(vsrc + (size_t)(g) * 4096,                 &vl[bufi][wave * 1024]); \
    GLLDS16(vsrc + (size_t)(g) * 4096 + 512,           &vl[bufi][wave * 1024 + 512]); \
  } while (0)

  STAGE_KV(c0, 0, 0);
  __syncthreads();

  for (int ib = 0; ib < nblk; ib++) {
    const int kb0 = c0 + ib * 32;
    if (ib + 1 < nblk) STAGE_KV(kb0 + 32, ib + 1, (ib + 1) & 1);  // T14: drained at barrier
    if (kb0 <= qlimB) {                       // wave-uniform
      const bool doA = (kb0 <= qlimA);
      const ushort* kcur = &kl[ib & 1][0];
      const ushort* vcur = &vl[ib & 1][0];
      bf16x8 kf0[4], kf1[4];
      #pragma unroll
      for (int kc = 0; kc < 4; kc++) {
        int u = quad + kc * 4;
        kf0[kc] = *(const bf16x8*)(kcur + col*128        + ((u ^ col) * 8));
        kf1[kc] = *(const bf16x8*)(kcur + (16 + col)*128 + ((u ^ col) * 8));
      }
      f32x4 sB0 = (f32x4){0.f,0.f,0.f,0.f}, sB1 = sB0, sA0 = sB0, sA1 = sB0;
      __builtin_amdgcn_s_setprio(1);
      #pragma unroll
      for (int kc = 0; kc < 4; kc++) {
        sB0 = __builtin_amdgcn_mfma_f32_16x16x32_bf16(kf0[kc], qfB[kc], sB0, 0, 0, 0);
        sB1 = __builtin_amdgcn_mfma_f32_16x16x32_bf16(kf1[kc], qfB[kc], sB1, 0, 0, 0);
      }
      if (doA) {
        #pragma unroll
        for (int kc = 0; kc < 4; kc++) {
          sA0 = __builtin_amdgcn_mfma_f32_16x16x32_bf16(kf0[kc], qfA[kc], sA0, 0, 0, 0);
          sA1 = __builtin_amdgcn_mfma_f32_16x16x32_bf16(kf1[kc], qfA[kc], sA1, 0, 0, 0);
        }
      }
      __builtin_amdgcn_s_setprio(0);
      bf16x8 vf03[4];
      #pragma unroll
      for (int j = 0; j < 4; j++)
        vf03[j] = *(const bf16x8*)(vcur + col * 32 + j * 512 + vru);
      // ---- tile B softmax ----
      uint4 pfB4;
      {
        float s[8];
        #pragma unroll
        for (int r = 0; r < 4; r++) { s[r] = sB0[r]; s[4+r] = sB1[r]; }
        if (kb0 + 31 > q0B) {
          #pragma unroll
          for (int r = 0; r < 4; r++) {
            if (kb0 + quad*4 + r      > q0B + col) s[r]   = -1e30f;
            if (kb0 + 16 + quad*4 + r > q0B + col) s[4+r] = -1e30f;
          }
        }
        float cm = s[0];
        #pragma unroll
        for (int j = 1; j < 8; j++) cm = fmaxf(cm, s[j]);
        cm = red4max(cm);
        if (!__all(cm <= mB)) {               // T13 exact skip
          float mn = fmaxf(mB, cm);
          float alpha = exp2f((mB - mn) * SL2E);
          lB *= alpha;
          #pragma unroll
          for (int d = 0; d < 8; d++) OB[d] *= alpha;
          mB = mn;
        }
        float rs = 0.f;
        #pragma unroll
        for (int j = 0; j < 8; j++) { s[j] = exp2f((s[j] - mB) * SL2E); rs += s[j]; }
        lB += red4sum(rs);
        unsigned w0 = cvt_pk_bf16(s[0], s[1]);
        unsigned w1 = cvt_pk_bf16(s[2], s[3]);
        unsigned w2 = cvt_pk_bf16(s[4], s[5]);
        unsigned w3 = cvt_pk_bf16(s[6], s[7]);
        pl32sw(w0, w2); pl32sw(w1, w3);
        pl16sw(w0, w2); pl16sw(w1, w3);
        pfB4 = make_uint4(w0, w1, w2, w3);
      }
      bf16x8 vf47[4];
      #pragma unroll
      for (int j = 0; j < 4; j++)
        vf47[j] = *(const bf16x8*)(vcur + col * 32 + (4 + j) * 512 + vru);
      // ---- tile A softmax ----
      uint4 pfA4 = make_uint4(0u, 0u, 0u, 0u);
      if (doA) {
        float s[8];
        #pragma unroll
        for (int r = 0; r < 4; r++) { s[r] = sA0[r]; s[4+r] = sA1[r]; }
        if (kb0 + 31 > q0A) {
          #pragma unroll
          for (int r = 0; r < 4; r++) {
            if (kb0 + quad*4 + r      > q0A + col) s[r]   = -1e30f;
            if (kb0 + 16 + quad*4 + r > q0A + col) s[4+r] = -1e30f;
          }
        }
        float cm = s[0];
        #pragma unroll
        for (int j = 1; j < 8; j++) cm = fmaxf(cm, s[j]);
        cm = red4max(cm);
        if (!__all(cm <= mA)) {
          float mn = fmaxf(mA, cm);
          float alpha = exp2f((mA - mn) * SL2E);
          lA *= alpha;
          #pragma unroll
          for (int d = 0; d < 8; d++) OA[d] *= alpha;
          mA = mn;
        }
        float rs = 0.f;
        #pragma unroll
        for (int j = 0; j < 8; j++) { s[j] = exp2f((s[j] - mA) * SL2E); rs += s[j]; }
        lA += red4sum(rs);
        unsigned w0 = cvt_pk_bf16(s[0], s[1]);
        unsigned w1 = cvt_pk_bf16(s[2], s[3]);
        unsigned w2 = cvt_pk_bf16(s[4], s[5]);
        unsigned w3 = cvt_pk_bf16(s[6], s[7]);
        pl32sw(w0, w2); pl32sw(w1, w3);
        pl16sw(w0, w2); pl16sw(w1, w3);
        pfA4 = make_uint4(w0, w1, w2, w3);
      }
      // ---- PV for both tiles (shared vf) ----
      {
        union { uint4 u4; bf16x8 v; } puB, puA;
        puB.u4 = pfB4; puA.u4 = pfA4;
        __builtin_amdgcn_s_setprio(1);
        #pragma unroll
        for (int j = 0; j < 4; j++)
          OB[j] = __builtin_amdgcn_mfma_f32_16x16x32_bf16(vf03[j], puB.v, OB[j], 0, 0, 0);
        if (doA) {
          #pragma unroll
          for (int j = 0; j < 4; j++)
            OA[j] = __builtin_amdgcn_mfma_f32_16x16x32_bf16(vf03[j], puA.v, OA[j], 0, 0, 0);
        }
        #pragma unroll
        for (int j = 0; j < 4; j++)
          OB[4 + j] = __builtin_amdgcn_mfma_f32_16x16x32_bf16(vf47[j], puB.v, OB[4 + j], 0, 0, 0);
        if (doA) {
          #pragma unroll
          for (int j = 0; j < 4; j++)
            OA[4 + j] = __builtin_amdgcn_mfma_f32_16x16x32_bf16(vf47[j], puA.v, OA[4 + j], 0, 0, 0);
        }
        __builtin_amdgcn_s_setprio(0);
      }
    }
    __syncthreads();                          // drains gllds vmcnt for next buffer
  }

  // f16 partial epilogue
  ushort* OpA = Opart + (size_t)slotA * (64 * 128) + (size_t)(wave*16 + col) * 128 + quad * 4;
  ushort* OpB = Opart + (size_t)slotB * (64 * 128) + (size_t)(wave*16 + col) * 128 + quad * 4;
  #pragma unroll
  for (int d = 0; d < 8; d++) {
    ushort4 ha, hb;
    ha.x = f2h(OA[d][0]); ha.y = f2h(OA[d][1]); ha.z = f2h(OA[d][2]); ha.w = f2h(OA[d][3]);
    hb.x = f2h(OB[d][0]); hb.y = f2h(OB[d][1]); hb.z = f2h(OB[d][2]); hb.w = f2h(OB[d][3]);
    *(ushort4*)(OpA + d * 16) = ha;
    *(ushort4*)(OpB + d * 16) = hb;
  }
  if (quad == 0) {
    *(float2*)(ml + (size_t)slotA * 128 + (size_t)(wave*16 + col) * 2) = make_float2(mA, lA);
    *(float2*)(ml + (size_t)slotB * 128 + (size_t)(wave*16 + col) * 2) = make_float2(mB, lB);
  }
}

// ---------- kernel 5: combine split-K partials (f16, two-pass, no local arrays) ----------
__global__ __launch_bounds__(256) void combine_kernel(const ushort* __restrict__ Opart,
    const float* __restrict__ ml, float* __restrict__ out) {
  const float SL2E = 0.08838834764831845f * 1.44269504088896340736f;
  int tile = blockIdx.x, b = blockIdx.y;
  int a = tile >> 3, rr = tile & 7;
  int nc = a + 1;
  int base = b * 288 + (a + 1) * (4 * a + rr);
  int tid = threadIdx.x;
  int row = tid >> 2;
  int cs = (tid & 3) * 4;
  float mstar = -1e30f;
  for (int ci = 0; ci < nc; ci++)
    mstar = fmaxf(mstar, ml[(size_t)(base + ci) * 128 + row * 2]);
  float denom = 0.f;
  f32x4 acc[8];
  #pragma unroll
  for (int i = 0; i < 8; i++) acc[i] = (f32x4){0.f,0.f,0.f,0.f};
  for (int ci = 0; ci < nc; ci++) {
    float mc = ml[(size_t)(base + ci) * 128 + row * 2];
    float lc = ml[(size_t)(base + ci) * 128 + row * 2 + 1];
    float w = exp2f((mc - mstar) * SL2E);
    denom += w * lc;
    const ushort* Op = Opart + (size_t)(base + ci) * (64 * 128) + row * 128;
    #pragma unroll
    for (int i = 0; i < 8; i++) {
      ushort4 h = *(const ushort4*)(Op + cs + i * 16);
      acc[i][0] += w * h2f(h.x);
      acc[i][1] += w * h2f(h.y);
      acc[i][2] += w * h2f(h.z);
      acc[i][3] += w * h2f(h.w);
    }
  }
  float inv = 1.f / denom;
  float* o = out + ((size_t)(b * S_) + tile * 64 + row) * H_;
  #pragma unroll
  for (int i = 0; i < 8; i++) {
    f32x4 v = acc[i] * inv;
    *(f32x4*)(o + cs + i * 16) = v;
  }
}

extern "C" void kernel_launch(void* const* d_in, const int* in_sizes, int n_in,
                              void* d_out, int out_size, void* d_ws, size_t ws_size,
                              hipStream_t stream) {
  (void)in_sizes; (void)n_in; (void)out_size; (void)ws_size;
  const float* x  = (const float*)d_in[0];
  const float* Wq = (const float*)d_in[1];
  const float* Wk = (const float*)d_in[2];
  const float* Wv = (const float*)d_in[3];
  float* out = (float*)d_out;
  char* ws = (char*)d_ws;
  ushort* Wt = (ushort*)ws;                                        // 768 KB
  ushort* qb = (ushort*)(ws + 786432);                             // 4 MB each
  ushort* kb = qb + (size_t)M_ * H_;
  ushort* vT = kb + (size_t)M_ * H_;
  ushort* Opart = (ushort*)(ws + 786432 + 3 * (size_t)M_ * H_ * 2); // f16, 18.9 MB
  float* ml = (float*)((char*)Opart + (size_t)M_ * E_ * 2);        // after 32 MB region

  hipLaunchKernelGGL(wt_kernel,   dim3(384), dim3(256), 0, stream, Wq, Wk, Wv, Wt);
  hipLaunchKernelGGL(qkv_gemm,    dim3(128, 3), dim3(256), 0, stream, x, Wt, qb, kb, vT);
  hipLaunchKernelGGL(flash_kernel,dim3(8, 32, 4), dim3(256), 0, stream, qb, kb, vT, Opart, ml);
  hipLaunchKernelGGL(combine_kernel, dim3(64, 4), dim3(256), 0, stream, Opart, ml, out);
}

// Round 13
// 200.456 us; speedup vs baseline: 1.0714x; 1.0035x over previous
//
#include <hip/hip_runtime.h>

#define B_ 4
#define S_ 4096
#define E_ 1024
#define H_ 128
#define M_ (B_*S_)   // 16384

typedef __attribute__((ext_vector_type(8))) short bf16x8;
typedef __attribute__((ext_vector_type(4))) float f32x4;
typedef __attribute__((ext_vector_type(2))) unsigned int uint2v;

__device__ inline ushort f2bf(float f) {
  union { float f; unsigned u; } v; v.f = f;
  unsigned r = v.u + 0x7fffu + ((v.u >> 16) & 1u);   // RNE
  return (ushort)(r >> 16);
}
__device__ inline ushort f2h(float f) {              // f32 -> f16 bits (RNE)
  union { _Float16 h; ushort u; } v; v.h = (_Float16)f; return v.u;
}
__device__ inline float h2f(ushort u) {
  union { ushort u; _Float16 h; } v; v.u = u; return (float)v.h;
}

// ---- gfx950 cross-lane primitives ----
__device__ inline void pl16sw(unsigned &x, unsigned &y) {
#if __has_builtin(__builtin_amdgcn_permlane16_swap)
  uint2v r = __builtin_amdgcn_permlane16_swap(x, y, false, false);
  x = r.x; y = r.y;
#else
  asm("v_permlane16_swap_b32 %0, %1" : "+v"(x), "+v"(y));
#endif
}
__device__ inline void pl32sw(unsigned &x, unsigned &y) {
#if __has_builtin(__builtin_amdgcn_permlane32_swap)
  uint2v r = __builtin_amdgcn_permlane32_swap(x, y, false, false);
  x = r.x; y = r.y;
#else
  asm("v_permlane32_swap_b32 %0, %1" : "+v"(x), "+v"(y));
#endif
}
__device__ inline float red4max(float v) {
  union { float f; unsigned u; } a, b;
  a.f = v; b.f = v; pl16sw(a.u, b.u);
  float m1 = fmaxf(a.f, b.f);
  a.f = m1; b.f = m1; pl32sw(a.u, b.u);
  return fmaxf(a.f, b.f);
}
__device__ inline float red4sum(float v) {
  union { float f; unsigned u; } a, b;
  a.f = v; b.f = v; pl16sw(a.u, b.u);
  float s1 = a.f + b.f;
  a.f = s1; b.f = s1; pl32sw(a.u, b.u);
  return a.f + b.f;
}
__device__ inline unsigned cvt_pk_bf16(float lo, float hi) {
  unsigned w;
  asm("v_cvt_pk_bf16_f32 %0, %1, %2" : "=v"(w) : "v"(lo), "v"(hi));
  return w;
}

#define GLLDS16(g, l) __builtin_amdgcn_global_load_lds( \
    (const __attribute__((address_space(1))) void*)(g), \
    (__attribute__((address_space(3))) void*)(l), 16, 0, 0)

// ---------- kernel 1: W [1024][128] f32 (x3) -> Wt [3][128][1024] bf16 ----------
__global__ __launch_bounds__(256) void wt_kernel(const float* __restrict__ Wq,
    const float* __restrict__ Wk, const float* __restrict__ Wv,
    ushort* __restrict__ Wt) {
  int bid = blockIdx.x;               // 384 = 3 mats * 4 h-tiles * 32 e-tiles
  int mat = bid >> 7;
  int rem = bid & 127;
  int ht = rem >> 5, et = rem & 31;
  const float* W = mat == 0 ? Wq : (mat == 1 ? Wk : Wv);
  int e0 = et * 32, h0 = ht * 32;
  __shared__ float tl[32][33];
  int t = threadIdx.x;
  int r = t >> 3, c = (t & 7) << 2;
  const float4 f = *(const float4*)(W + (size_t)(e0 + r) * H_ + h0 + c);
  tl[r][c] = f.x; tl[r][c+1] = f.y; tl[r][c+2] = f.z; tl[r][c+3] = f.w;
  __syncthreads();
  ushort4 o;
  o.x = f2bf(tl[c+0][r]); o.y = f2bf(tl[c+1][r]);
  o.z = f2bf(tl[c+2][r]); o.w = f2bf(tl[c+3][r]);
  *(ushort4*)(Wt + ((size_t)mat*H_ + h0 + r) * E_ + e0 + c) = o;
}

// ---------- kernel 2: QKV GEMM, FUSED x f32->bf16 conversion in A-staging ----------
__global__ __launch_bounds__(256, 2) void qkv_gemm(const float* __restrict__ x,
    const ushort* __restrict__ Wt, ushort* __restrict__ qo,
    ushort* __restrict__ ko, ushort* __restrict__ vTo) {
  const int m0 = blockIdx.x * 128;
  const int mat = blockIdx.y;
  const ushort* Bsrc = Wt + (size_t)mat * H_ * E_;
  __shared__ ushort As[2][128 * 64];
  __shared__ ushort Bs[2][128 * 64];
  const int tid = threadIdx.x;
  const int wave = tid >> 6, lane = tid & 63;
  const int col = lane & 15, quad = lane >> 4;
  const int wr = wave >> 1, wc = wave & 1;

  f32x4 acc[4][4];
  #pragma unroll
  for (int i = 0; i < 4; i++)
    #pragma unroll
    for (int j = 0; j < 4; j++) acc[i][j] = (f32x4){0.f,0.f,0.f,0.f};

  const int srow = lane >> 3;
  const int sunit = (lane & 7) ^ srow;
  const int gcol = sunit * 8;
  const int lwoff = (lane & 7) * 8;   // linear LDS unit for A ds_writes

  float4 fa[4][2];
  #define STAGE_A_LOAD(it) do { \
    _Pragma("unroll") \
    for (int j = 0; j < 4; j++) { \
      const float* xp = x + (size_t)(m0 + wave*8 + j*32 + srow) * E_ + (it)*64 + gcol; \
      fa[j][0] = *(const float4*)xp; \
      fa[j][1] = *(const float4*)(xp + 4); \
    } \
  } while (0)
  #define STAGE_A_WRITE(bufi) do { \
    _Pragma("unroll") \
    for (int j = 0; j < 4; j++) { \
      uint4 u = make_uint4(cvt_pk_bf16(fa[j][0].x, fa[j][0].y), \
                           cvt_pk_bf16(fa[j][0].z, fa[j][0].w), \
                           cvt_pk_bf16(fa[j][1].x, fa[j][1].y), \
                           cvt_pk_bf16(fa[j][1].z, fa[j][1].w)); \
      *(uint4*)(&As[bufi][(wave*8 + j*32 + srow) * 64 + lwoff]) = u; \
    } \
  } while (0)
  #define STAGE_B(it, bufi) do { \
    _Pragma("unroll") \
    for (int j = 0; j < 4; j++) { \
      int rbase = wave*8 + j*32; \
      GLLDS16(Bsrc + (size_t)(rbase + srow) * E_ + (it)*64 + gcol, \
              &Bs[bufi][rbase * 64]); \
    } \
  } while (0)

  STAGE_A_LOAD(0);
  STAGE_B(0, 0);
  STAGE_A_WRITE(0);
  __syncthreads();

  for (int it = 0; it < 16; it++) {
    if (it < 15) { STAGE_A_LOAD(it + 1); STAGE_B(it + 1, (it + 1) & 1); }
    const ushort* a = &As[it & 1][0];
    const ushort* bb = &Bs[it & 1][0];
    #pragma unroll
    for (int kc = 0; kc < 2; kc++) {
      bf16x8 af[4], bf[4];
      #pragma unroll
      for (int mi = 0; mi < 4; mi++) {
        int rr = wr*64 + mi*16 + col;
        af[mi] = *(const bf16x8*)(a + rr*64 + (((kc*4 + quad) ^ (col & 7)) * 8));
      }
      #pragma unroll
      for (int ni = 0; ni < 4; ni++) {
        int rr = wc*64 + ni*16 + col;
        bf[ni] = *(const bf16x8*)(bb + rr*64 + (((kc*4 + quad) ^ (col & 7)) * 8));
      }
      #pragma unroll
      for (int mi = 0; mi < 4; mi++)
        #pragma unroll
        for (int ni = 0; ni < 4; ni++)
          acc[mi][ni] = __builtin_amdgcn_mfma_f32_16x16x32_bf16(af[mi], bf[ni], acc[mi][ni], 0, 0, 0);
    }
    if (it < 15) STAGE_A_WRITE((it + 1) & 1);   // loads had MFMA-time to land
    __syncthreads();
  }

  if (mat == 2) {
    int bb = m0 >> 12;
    int sbase = (m0 & 4095) + wr * 64;
    #pragma unroll
    for (int ni = 0; ni < 4; ni++) {
      int n = wc*64 + ni*16 + col;
      #pragma unroll
      for (int mi = 0; mi < 4; mi++) {
        int s = sbase + mi*16 + quad*4;
        ushort4 o;
        o.x = f2bf(acc[mi][ni][0]); o.y = f2bf(acc[mi][ni][1]);
        o.z = f2bf(acc[mi][ni][2]); o.w = f2bf(acc[mi][ni][3]);
        *(ushort4*)(vTo + ((size_t)(bb * 128 + (s >> 5)) * 128 + n) * 32 + (s & 31)) = o;
      }
    }
  } else {
    ushort* dst = (mat == 0 ? qo : ko);
    #pragma unroll
    for (int ni = 0; ni < 4; ni++) {
      int n = wc*64 + ni*16 + col;
      #pragma unroll
      for (int mi = 0; mi < 4; mi++) {
        int row = m0 + wr*64 + mi*16 + quad*4;
        #pragma unroll
        for (int r = 0; r < 4; r++)
          dst[(size_t)(row + r) * H_ + n] = f2bf(acc[mi][ni][r]);
      }
    }
  }
}

// ---------- kernel 4: causal flash, HALF-PAIR per 2-wave block (128 thr) ----------
// R13: flash is latency-bound at a fixed 2 waves/SIMD register cap; all 4 waves of a
// 256-thr block were barrier-coupled into the same phase (2 independent groups/CU,
// aligned stalls). 2-wave blocks keep the per-wave body BYTE-IDENTICAL (pair
// structure preserved -- the shape the backend allocates fat) but give 4 independent
// barrier groups/CU: one group's staging drain overlaps another's MFMA/softmax.
// Each block: 32 q-rows of tA + 32 of tB (h = half), full 32-key K/V tile staging
// split across 2 waves (4+4 gllds each). Grid (8, 64, 4), 1152 active blocks.
#define CHUNK_ 512
__global__ __launch_bounds__(128, 2) void flash_kernel(const ushort* __restrict__ q,
    const ushort* __restrict__ k, const ushort* __restrict__ vT,
    ushort* __restrict__ Opart, float* __restrict__ ml) {
  const float SL2E = 0.08838834764831845f * 1.44269504088896340736f;
  int c = blockIdx.x;
  int hp = 63 - (int)blockIdx.y;              // heavy half-pairs first
  int tp = hp >> 1, h = hp & 1;
  int b = blockIdx.z;
  if (tp < 4 * c) return;
  int tA = tp * 2, tB = tA + 1;
  int aA = tA >> 3, rA = tA & 7;
  int aB = tB >> 3, rB = tB & 7;
  int slotA = b * 288 + (aA + 1) * (4 * aA + rA) + c;
  int slotB = b * 288 + (aB + 1) * (4 * aB + rB) + c;

  int wave = threadIdx.x >> 6, lane = threadIdx.x & 63;
  int col = lane & 15, quad = lane >> 4;
  int row0 = h * 32 + wave * 16;              // row offset within the 64-row tiles
  int q0A = tA * 64 + row0;
  int q0B = q0A + 64;
  const ushort* qb = q + (size_t)b * S_ * H_;
  const ushort* kbp = k + (size_t)b * S_ * H_;
  const ushort* vb = vT + (size_t)b * S_ * H_;

  __shared__ ushort kl[2][32 * 128];          // K double-buffer (16 KB), src-side swizzle
  __shared__ ushort vl[2][32 * 128];          // V double-buffer (16 KB), src-side swizzle

  bf16x8 qfA[4], qfB[4];
  {
    const ushort* qpA = qb + (size_t)(q0A + col) * H_ + quad * 8;
    const ushort* qpB = qb + (size_t)(q0B + col) * H_ + quad * 8;
    #pragma unroll
    for (int kc = 0; kc < 4; kc++) {
      qfA[kc] = *(const bf16x8*)(qpA + kc * 32);
      qfB[kc] = *(const bf16x8*)(qpB + kc * 32);
    }
  }

  f32x4 OA[8], OB[8];
  #pragma unroll
  for (int d = 0; d < 8; d++) { OA[d] = (f32x4){0.f,0.f,0.f,0.f}; OB[d] = (f32x4){0.f,0.f,0.f,0.f}; }
  float mA = -1e30f, lA = 0.f, mB = -1e30f, lB = 0.f;

  const int c0 = c * CHUNK_;
  const int kendWG = min(c0 + CHUNK_, tB * 64 + 64);
  const int nblk = (kendWG - c0 + 31) >> 5;
  const int qlimA = q0A + 15, qlimB = q0B + 15;

  // K staging: wave covers rows wave*16 + j*4 + quad (j=0..3), unit col.
  // gu depends on row&15 = (j*4+quad) for both waves (wave*16 drops out mod 16).
  const int guK = (col ^ (quad & 15));        // base; per-j XOR added below (j*4)
  // V source: per-wave chunk base wave*2048; swizzle sel = (lane>>3)&3 (verified
  // invariant: dim = wave*64 + j*16 + (lane>>2), sel=(dim>>1)&3 reduces to (lane>>3)&3).
  const ushort* vsrc = vb + (size_t)c * 16 * 4096 + (size_t)wave * 2048
                     + (lane >> 2) * 32 + (((lane & 3) ^ ((lane >> 3) & 3)) * 8);
  const int vru = ((quad ^ ((col >> 1) & 3)) * 8);

  #define STAGE_KV(kb, g, bufi) do { \
    _Pragma("unroll") \
    for (int j = 0; j < 4; j++) { \
      int sk = wave * 16 + j * 4 + quad; \
      GLLDS16(kbp + (size_t)((kb) + sk) * H_ + ((col ^ (sk & 15)) * 8), \
              &kl[bufi][wave * 2048 + j * 512]); \
      GLLDS16(vsrc + (size_t)(g) * 4096 + j * 512, \
              &vl[bufi][wave * 2048 + j * 512]); \
    } \
  } while (0)

  STAGE_KV(c0, 0, 0);
  __syncthreads();

  for (int ib = 0; ib < nblk; ib++) {
    const int kb0 = c0 + ib * 32;
    if (ib + 1 < nblk) STAGE_KV(kb0 + 32, ib + 1, (ib + 1) & 1);  // T14: drained at barrier
    if (kb0 <= qlimB) {                       // wave-uniform
      const bool doA = (kb0 <= qlimA);
      const ushort* kcur = &kl[ib & 1][0];
      const ushort* vcur = &vl[ib & 1][0];
      bf16x8 kf0[4], kf1[4];
      #pragma unroll
      for (int kc = 0; kc < 4; kc++) {
        int u = quad + kc * 4;
        kf0[kc] = *(const bf16x8*)(kcur + col*128        + ((u ^ col) * 8));
        kf1[kc] = *(const bf16x8*)(kcur + (16 + col)*128 + ((u ^ col) * 8));
      }
      f32x4 sB0 = (f32x4){0.f,0.f,0.f,0.f}, sB1 = sB0, sA0 = sB0, sA1 = sB0;
      __builtin_amdgcn_s_setprio(1);
      #pragma unroll
      for (int kc = 0; kc < 4; kc++) {
        sB0 = __builtin_amdgcn_mfma_f32_16x16x32_bf16(kf0[kc], qfB[kc], sB0, 0, 0, 0);
        sB1 = __builtin_amdgcn_mfma_f32_16x16x32_bf16(kf1[kc], qfB[kc], sB1, 0, 0, 0);
      }
      if (doA) {
        #pragma unroll
        for (int kc = 0; kc < 4; kc++) {
          sA0 = __builtin_amdgcn_mfma_f32_16x16x32_bf16(kf0[kc], qfA[kc], sA0, 0, 0, 0);
          sA1 = __builtin_amdgcn_mfma_f32_16x16x32_bf16(kf1[kc], qfA[kc], sA1, 0, 0, 0);
        }
      }
      __builtin_amdgcn_s_setprio(0);
      bf16x8 vf03[4];
      #pragma unroll
      for (int j = 0; j < 4; j++)
        vf03[j] = *(const bf16x8*)(vcur + col * 32 + j * 512 + vru);
      // ---- tile B softmax ----
      uint4 pfB4;
      {
        float s[8];
        #pragma unroll
        for (int r = 0; r < 4; r++) { s[r] = sB0[r]; s[4+r] = sB1[r]; }
        if (kb0 + 31 > q0B) {
          #pragma unroll
          for (int r = 0; r < 4; r++) {
            if (kb0 + quad*4 + r      > q0B + col) s[r]   = -1e30f;
            if (kb0 + 16 + quad*4 + r > q0B + col) s[4+r] = -1e30f;
          }
        }
        float cm = s[0];
        #pragma unroll
        for (int j = 1; j < 8; j++) cm = fmaxf(cm, s[j]);
        cm = red4max(cm);
        if (!__all(cm <= mB)) {               // T13 exact skip
          float mn = fmaxf(mB, cm);
          float alpha = exp2f((mB - mn) * SL2E);
          lB *= alpha;
          #pragma unroll
          for (int d = 0; d < 8; d++) OB[d] *= alpha;
          mB = mn;
        }
        float rs = 0.f;
        #pragma unroll
        for (int j = 0; j < 8; j++) { s[j] = exp2f((s[j] - mB) * SL2E); rs += s[j]; }
        lB += red4sum(rs);
        unsigned w0 = cvt_pk_bf16(s[0], s[1]);
        unsigned w1 = cvt_pk_bf16(s[2], s[3]);
        unsigned w2 = cvt_pk_bf16(s[4], s[5]);
        unsigned w3 = cvt_pk_bf16(s[6], s[7]);
        pl32sw(w0, w2); pl32sw(w1, w3);
        pl16sw(w0, w2); pl16sw(w1, w3);
        pfB4 = make_uint4(w0, w1, w2, w3);
      }
      bf16x8 vf47[4];
      #pragma unroll
      for (int j = 0; j < 4; j++)
        vf47[j] = *(const bf16x8*)(vcur + col * 32 + (4 + j) * 512 + vru);
      // ---- tile A softmax ----
      uint4 pfA4 = make_uint4(0u, 0u, 0u, 0u);
      if (doA) {
        float s[8];
        #pragma unroll
        for (int r = 0; r < 4; r++) { s[r] = sA0[r]; s[4+r] = sA1[r]; }
        if (kb0 + 31 > q0A) {
          #pragma unroll
          for (int r = 0; r < 4; r++) {
            if (kb0 + quad*4 + r      > q0A + col) s[r]   = -1e30f;
            if (kb0 + 16 + quad*4 + r > q0A + col) s[4+r] = -1e30f;
          }
        }
        float cm = s[0];
        #pragma unroll
        for (int j = 1; j < 8; j++) cm = fmaxf(cm, s[j]);
        cm = red4max(cm);
        if (!__all(cm <= mA)) {
          float mn = fmaxf(mA, cm);
          float alpha = exp2f((mA - mn) * SL2E);
          lA *= alpha;
          #pragma unroll
          for (int d = 0; d < 8; d++) OA[d] *= alpha;
          mA = mn;
        }
        float rs = 0.f;
        #pragma unroll
        for (int j = 0; j < 8; j++) { s[j] = exp2f((s[j] - mA) * SL2E); rs += s[j]; }
        lA += red4sum(rs);
        unsigned w0 = cvt_pk_bf16(s[0], s[1]);
        unsigned w1 = cvt_pk_bf16(s[2], s[3]);
        unsigned w2 = cvt_pk_bf16(s[4], s[5]);
        unsigned w3 = cvt_pk_bf16(s[6], s[7]);
        pl32sw(w0, w2); pl32sw(w1, w3);
        pl16sw(w0, w2); pl16sw(w1, w3);
        pfA4 = make_uint4(w0, w1, w2, w3);
      }
      // ---- PV for both tiles (shared vf) ----
      {
        union { uint4 u4; bf16x8 v; } puB, puA;
        puB.u4 = pfB4; puA.u4 = pfA4;
        __builtin_amdgcn_s_setprio(1);
        #pragma unroll
        for (int j = 0; j < 4; j++)
          OB[j] = __builtin_amdgcn_mfma_f32_16x16x32_bf16(vf03[j], puB.v, OB[j], 0, 0, 0);
        if (doA) {
          #pragma unroll
          for (int j = 0; j < 4; j++)
            OA[j] = __builtin_amdgcn_mfma_f32_16x16x32_bf16(vf03[j], puA.v, OA[j], 0, 0, 0);
        }
        #pragma unroll
        for (int j = 0; j < 4; j++)
          OB[4 + j] = __builtin_amdgcn_mfma_f32_16x16x32_bf16(vf47[j], puB.v, OB[4 + j], 0, 0, 0);
        if (doA) {
          #pragma unroll
          for (int j = 0; j < 4; j++)
            OA[4 + j] = __builtin_amdgcn_mfma_f32_16x16x32_bf16(vf47[j], puA.v, OA[4 + j], 0, 0, 0);
        }
        __builtin_amdgcn_s_setprio(0);
      }
    }
    __syncthreads();                          // drains gllds vmcnt for next buffer
  }

  // f16 partial epilogue (rows row0..row0+15 of each 64-row tile)
  ushort* OpA = Opart + (size_t)slotA * (64 * 128) + (size_t)(row0 + col) * 128 + quad * 4;
  ushort* OpB = Opart + (size_t)slotB * (64 * 128) + (size_t)(row0 + col) * 128 + quad * 4;
  #pragma unroll
  for (int d = 0; d < 8; d++) {
    ushort4 ha, hb;
    ha.x = f2h(OA[d][0]); ha.y = f2h(OA[d][1]); ha.z = f2h(OA[d][2]); ha.w = f2h(OA[d][3]);
    hb.x = f2h(OB[d][0]); hb.y = f2h(OB[d][1]); hb.z = f2h(OB[d][2]); hb.w = f2h(OB[d][3]);
    *(ushort4*)(OpA + d * 16) = ha;
    *(ushort4*)(OpB + d * 16) = hb;
  }
  if (quad == 0) {
    *(float2*)(ml + (size_t)slotA * 128 + (size_t)(row0 + col) * 2) = make_float2(mA, lA);
    *(float2*)(ml + (size_t)slotB * 128 + (size_t)(row0 + col) * 2) = make_float2(mB, lB);
  }
}

// ---------- kernel 5: combine split-K partials (f16, two-pass, no local arrays) ----------
__global__ __launch_bounds__(256) void combine_kernel(const ushort* __restrict__ Opart,
    const float* __restrict__ ml, float* __restrict__ out) {
  const float SL2E = 0.08838834764831845f * 1.44269504088896340736f;
  int tile = blockIdx.x, b = blockIdx.y;
  int a = tile >> 3, rr = tile & 7;
  int nc = a + 1;
  int base = b * 288 + (a + 1) * (4 * a + rr);
  int tid = threadIdx.x;
  int row = tid >> 2;
  int cs = (tid & 3) * 4;
  float mstar = -1e30f;
  for (int ci = 0; ci < nc; ci++)
    mstar = fmaxf(mstar, ml[(size_t)(base + ci) * 128 + row * 2]);
  float denom = 0.f;
  f32x4 acc[8];
  #pragma unroll
  for (int i = 0; i < 8; i++) acc[i] = (f32x4){0.f,0.f,0.f,0.f};
  for (int ci = 0; ci < nc; ci++) {
    float mc = ml[(size_t)(base + ci) * 128 + row * 2];
    float lc = ml[(size_t)(base + ci) * 128 + row * 2 + 1];
    float w = exp2f((mc - mstar) * SL2E);
    denom += w * lc;
    const ushort* Op = Opart + (size_t)(base + ci) * (64 * 128) + row * 128;
    #pragma unroll
    for (int i = 0; i < 8; i++) {
      ushort4 h = *(const ushort4*)(Op + cs + i * 16);
      acc[i][0] += w * h2f(h.x);
      acc[i][1] += w * h2f(h.y);
      acc[i][2] += w * h2f(h.z);
      acc[i][3] += w * h2f(h.w);
    }
  }
  float inv = 1.f / denom;
  float* o = out + ((size_t)(b * S_) + tile * 64 + row) * H_;
  #pragma unroll
  for (int i = 0; i < 8; i++) {
    f32x4 v = acc[i] * inv;
    *(f32x4*)(o + cs + i * 16) = v;
  }
}

extern "C" void kernel_launch(void* const* d_in, const int* in_sizes, int n_in,
                              void* d_out, int out_size, void* d_ws, size_t ws_size,
                              hipStream_t stream) {
  (void)in_sizes; (void)n_in; (void)out_size; (void)ws_size;
  const float* x  = (const float*)d_in[0];
  const float* Wq = (const float*)d_in[1];
  const float* Wk = (const float*)d_in[2];
  const float* Wv = (const float*)d_in[3];
  float* out = (float*)d_out;
  char* ws = (char*)d_ws;
  ushort* Wt = (ushort*)ws;                                        // 768 KB
  ushort* qb = (ushort*)(ws + 786432);                             // 4 MB each
  ushort* kb = qb + (size_t)M_ * H_;
  ushort* vT = kb + (size_t)M_ * H_;
  ushort* Opart = (ushort*)(ws + 786432 + 3 * (size_t)M_ * H_ * 2); // f16, 18.9 MB
  float* ml = (float*)((char*)Opart + (size_t)M_ * E_ * 2);        // after 32 MB region

  hipLaunchKernelGGL(wt_kernel,   dim3(384), dim3(256), 0, stream, Wq, Wk, Wv, Wt);
  hipLaunchKernelGGL(qkv_gemm,    dim3(128, 3), dim3(256), 0, stream, x, Wt, qb, kb, vT);
  hipLaunchKernelGGL(flash_kernel,dim3(8, 64, 4), dim3(128), 0, stream, qb, kb, vT, Opart, ml);
  hipLaunchKernelGGL(combine_kernel, dim3(64, 4), dim3(256), 0, stream, Opart, ml, out);
}